// Round 1
// baseline (431.511 us; speedup 1.0000x reference)
//
#include <hip/hip_runtime.h>
#include <stdint.h>
#include <math.h>

#define NA 256
#define HIDD 256
#define OBSD 128

// ---------------- threefry2x32 (JAX-exact) ----------------
__device__ __forceinline__ uint32_t rotl32_(uint32_t v, int d) {
    return (v << d) | (v >> (32 - d));
}

// Returns the bits for flat index `flat` of jax.random.uniform(key=(0,key_lo), shape size 131072)
__device__ uint32_t jax_random_bits(uint32_t key_lo, uint32_t flat) {
    uint32_t a, b;
    bool first;
    if (flat < 65536u) { a = flat; b = flat + 65536u; first = true; }
    else               { a = flat - 65536u; b = flat; first = false; }
    uint32_t ks0 = 0u, ks1 = key_lo, ks2 = 0u ^ key_lo ^ 0x1BD11BDAu;
    uint32_t x0 = a + ks0, x1 = b + ks1;
    const int r0[4] = {13, 15, 26, 6};
    const int r1[4] = {17, 29, 16, 24};
#define TF_R4(RS) { for (int rr = 0; rr < 4; ++rr) { x0 += x1; x1 = rotl32_(x1, RS[rr]); x1 ^= x0; } }
    TF_R4(r0); x0 += ks1; x1 += ks2 + 1u;
    TF_R4(r1); x0 += ks2; x1 += ks0 + 2u;
    TF_R4(r0); x0 += ks0; x1 += ks1 + 3u;
    TF_R4(r1); x0 += ks1; x1 += ks2 + 4u;
    TF_R4(r0); x0 += ks2; x1 += ks0 + 5u;
#undef TF_R4
    return first ? x0 : x1;
}

__device__ float jax_gumbel(uint32_t key_lo, uint32_t flat) {
    uint32_t bits = jax_random_bits(key_lo, flat);
    uint32_t v = (bits >> 9) | 0x3F800000u;
    float u = __uint_as_float(v) - 1.0f;     // [0, 1-2^-24]
    u = u + 1e-10f;                          // scale==1.0f in f32, so just +minval
    u = fmaxf(1e-10f, u);
    return -logf(-logf(u));
}

// ---------------- fused obs-proj + LSTM cell ----------------
__global__ void k_lstm(const float* __restrict__ obs, const float* __restrict__ hs,
                       const float* __restrict__ cs,
                       const float* __restrict__ w_obs, const float* __restrict__ b_obs,
                       const float* __restrict__ w_ih, const float* __restrict__ b_ih,
                       const float* __restrict__ w_hh, const float* __restrict__ b_hh,
                       float* __restrict__ h_out, float* __restrict__ c_out) {
    __shared__ float o_l[OBSD], h_l[HIDD], x_l[HIDD];
    int i = blockIdx.x, t = threadIdx.x;
    if (t < OBSD) o_l[t] = obs[i * OBSD + t];
    h_l[t] = hs[i * HIDD + t];
    __syncthreads();
    float x = b_obs[t];
    for (int k = 0; k < OBSD; ++k) x += o_l[k] * w_obs[k * HIDD + t];
    x_l[t] = x;
    __syncthreads();
    float g[4];
    for (int gi = 0; gi < 4; ++gi) {
        int col = gi * HIDD + t;
        float acc = b_ih[col] + b_hh[col];
        for (int k = 0; k < HIDD; ++k) acc += x_l[k] * w_ih[k * 1024 + col];
        for (int k = 0; k < HIDD; ++k) acc += h_l[k] * w_hh[k * 1024 + col];
        g[gi] = acc;
    }
    float ig = 1.f / (1.f + expf(-g[0]));
    float fg = 1.f / (1.f + expf(-g[1]));
    float gg = tanhf(g[2]);
    float og = 1.f / (1.f + expf(-g[3]));
    float cn = fg * cs[i * HIDD + t] + ig * gg;
    float hn = og * tanhf(cn);
    h_out[i * HIDD + t] = hn;
    c_out[i * HIDD + t] = cn;
}

// ---------------- generic row-per-block linear: Y[i] = X[i] @ W (+ b) ----------------
__global__ void k_lin(const float* __restrict__ X, const float* __restrict__ W,
                      const float* __restrict__ b, float* __restrict__ Y,
                      int K, int Nout) {
    __shared__ float xr[512];
    int i = blockIdx.x, t = threadIdx.x;
    for (int k = t; k < K; k += 256) xr[k] = X[i * K + k];
    __syncthreads();
    for (int n = t; n < Nout; n += 256) {
        float acc = b ? b[n] : 0.f;
        for (int k = 0; k < K; ++k) acc += xr[k] * W[k * Nout + n];
        Y[i * Nout + n] = acc;
    }
}

// ---------------- scheduler pairwise MLP + gumbel argmax -> adjacency ----------------
// z1[i,j] = relu(A[i] + B[j])  (b1 folded into A); z2 = relu(z1@w2+b2); l = z2@w3+b3
// adj[i,j] = (l1 + g1 > l0 + g0)
__global__ void k_sched(const float* __restrict__ A, const float* __restrict__ B,
                        const float* __restrict__ w2, const float* __restrict__ b2,
                        const float* __restrict__ w3, const float* __restrict__ b3,
                        float* __restrict__ adj, uint32_t key_lo) {
    __shared__ float a_l[128];
    __shared__ float w2_l[128 * 32];
    __shared__ float z1_l[8][128];
    __shared__ float b2_l[32];
    __shared__ float w3_l[64];
    __shared__ float b3_l[2];
    int i = blockIdx.x, t = threadIdx.x;
    if (t < 128) a_l[t] = A[i * 128 + t];
    for (int k = t; k < 4096; k += 256) w2_l[k] = w2[k];
    if (t < 32) b2_l[t] = b2[t];
    if (t < 64) w3_l[t] = w3[t];
    if (t < 2) b3_l[t] = b3[t];
    __syncthreads();
    int jj = t >> 5, k2 = t & 31;
    for (int j0 = 0; j0 < 256; j0 += 8) {
        for (int idx = t; idx < 1024; idx += 256) {
            int jl = idx >> 7, k = idx & 127;
            float v = a_l[k] + B[(j0 + jl) * 128 + k];
            z1_l[jl][k] = v > 0.f ? v : 0.f;
        }
        __syncthreads();
        float acc = b2_l[k2];
        for (int k = 0; k < 128; ++k) acc += z1_l[jj][k] * w2_l[k * 32 + k2];
        acc = acc > 0.f ? acc : 0.f;
        float p0 = acc * w3_l[2 * k2], p1 = acc * w3_l[2 * k2 + 1];
        for (int off = 16; off; off >>= 1) {
            p0 += __shfl_xor(p0, off);
            p1 += __shfl_xor(p1, off);
        }
        if (k2 == 0) {
            int j = j0 + jj;
            float l0 = p0 + b3_l[0], l1 = p1 + b3_l[1];
            uint32_t flat = (uint32_t)(i * 256 + j) * 2u;
            float g0 = jax_gumbel(key_lo, flat);
            float g1 = jax_gumbel(key_lo, flat + 1u);
            adj[i * 256 + j] = (l1 + g1 > l0 + g0) ? 1.0f : 0.0f;
        }
        __syncthreads();
    }
}

// ---------------- GAT attention coefficients ci/cj ----------------
__global__ void k_attcoef(const float* __restrict__ H, const float* __restrict__ ai,
                          const float* __restrict__ aj, float* __restrict__ ci,
                          float* __restrict__ cj, int heads, int F) {
    int n = blockIdx.x, lane = threadIdx.x; // 64 threads
    for (int h = 0; h < heads; ++h) {
        float pi = 0.f, pj = 0.f;
        for (int f = lane; f < F; f += 64) {
            float v = H[n * heads * F + h * F + f];
            pi += v * ai[h * F + f];
            pj += v * aj[h * F + f];
        }
        for (int off = 32; off; off >>= 1) {
            pi += __shfl_xor(pi, off);
            pj += __shfl_xor(pj, off);
        }
        if (lane == 0) { ci[n * heads + h] = pi; cj[n * heads + h] = pj; }
    }
}

// ---------------- GAT layer 1 (4 heads, concat, +bias, elu) ----------------
__global__ void k_gat1(const float* __restrict__ H, const float* __restrict__ adj,
                       const float* __restrict__ ci, const float* __restrict__ cj,
                       const float* __restrict__ bias, float* __restrict__ out) {
    __shared__ float att[4 * 256];
    int i = blockIdx.x, t = threadIdx.x;
    float adjv = (t == i) ? 1.f : adj[i * 256 + t];
    for (int h = 0; h < 4; ++h) {
        float e = ci[i * 4 + h] + cj[t * 4 + h];
        e = e >= 0.f ? e : 0.2f * e;
        att[h * 256 + t] = adjv > 0.f ? e : -INFINITY;
    }
    __syncthreads();
    int wv = t >> 6, lane = t & 63;
    {
        int h = wv;
        float m = -INFINITY;
        for (int j = lane; j < 256; j += 64) m = fmaxf(m, att[h * 256 + j]);
        for (int off = 32; off; off >>= 1) m = fmaxf(m, __shfl_xor(m, off));
        float vals[4];
        float s = 0.f;
        for (int r = 0; r < 4; ++r) {
            int j = lane + 64 * r;
            float v = expf(att[h * 256 + j] - m);
            vals[r] = v; s += v;
        }
        for (int off = 32; off; off >>= 1) s += __shfl_xor(s, off);
        float inv = 1.f / s;
        for (int r = 0; r < 4; ++r) { int j = lane + 64 * r; att[h * 256 + j] = vals[r] * inv; }
    }
    __syncthreads();
    for (int o = t; o < 512; o += 256) {
        int h = o >> 7, f = o & 127;
        float acc = 0.f;
        for (int j = 0; j < 256; ++j) acc += att[h * 256 + j] * H[j * 512 + h * 128 + f];
        acc += bias[o];
        out[i * 512 + o] = acc > 0.f ? acc : expm1f(acc);
    }
}

// ---------------- GAT layer 2 (1 head, average==identity, +bias) ----------------
__global__ void k_gat2(const float* __restrict__ H, const float* __restrict__ adj,
                       const float* __restrict__ ci, const float* __restrict__ cj,
                       const float* __restrict__ bias, float* __restrict__ out) {
    __shared__ float att[256];
    int i = blockIdx.x, t = threadIdx.x;
    float adjv = (t == i) ? 1.f : adj[i * 256 + t];
    float e = ci[i] + cj[t];
    e = e >= 0.f ? e : 0.2f * e;
    att[t] = adjv > 0.f ? e : -INFINITY;
    __syncthreads();
    int lane = t & 63;
    float m = -INFINITY;
    for (int j = lane; j < 256; j += 64) m = fmaxf(m, att[j]);
    for (int off = 32; off; off >>= 1) m = fmaxf(m, __shfl_xor(m, off));
    float s = 0.f;
    for (int j = lane; j < 256; j += 64) s += expf(att[j] - m);
    for (int off = 32; off; off >>= 1) s += __shfl_xor(s, off);
    float inv = 1.f / s;
    float myval = expf(att[t] - m) * inv;
    __syncthreads();
    att[t] = myval;
    __syncthreads();
    float acc = 0.f;
    for (int j = 0; j < 256; ++j) acc += att[j] * H[j * 256 + t];
    out[i * 256 + t] = acc + bias[t];
}

// ---------------- value + action heads ----------------
__global__ void k_head(const float* __restrict__ h_new, const float* __restrict__ comm,
                       const float* __restrict__ w_v, const float* __restrict__ b_v,
                       const float* __restrict__ w_a, const float* __restrict__ b_a,
                       float* __restrict__ value, float* __restrict__ action) {
    int i = blockIdx.x, lane = threadIdx.x; // 64 threads
    float p = 0.f;
    for (int k = lane; k < 256; k += 64)
        p += h_new[i * 256 + k] * w_v[k] + comm[i * 256 + k] * w_v[256 + k];
    for (int off = 32; off; off >>= 1) p += __shfl_xor(p, off);
    if (lane == 0) value[i] = p + b_v[0];

    float logit = -INFINITY;
    if (lane < 10) {
        float acc = b_a[lane];
        for (int k = 0; k < 256; ++k) acc += h_new[i * 256 + k] * w_a[k * 10 + lane];
        for (int k = 0; k < 256; ++k) acc += comm[i * 256 + k] * w_a[(256 + k) * 10 + lane];
        logit = acc;
    }
    float m = logit;
    for (int off = 8; off; off >>= 1) m = fmaxf(m, __shfl_xor(m, off));
    float ex = (lane < 10) ? expf(logit - m) : 0.f;
    float s = ex;
    for (int off = 8; off; off >>= 1) s += __shfl_xor(s, off);
    if (lane < 10) action[i * 10 + lane] = logit - m - logf(s);
}

extern "C" void kernel_launch(void* const* d_in, const int* in_sizes, int n_in,
                              void* d_out, int out_size, void* d_ws, size_t ws_size,
                              hipStream_t stream) {
    const float* obs   = (const float*)d_in[0];
    const float* hs    = (const float*)d_in[1];
    const float* cs    = (const float*)d_in[2];
    const float* w_obs = (const float*)d_in[3];
    const float* b_obs = (const float*)d_in[4];
    const float* w_ih  = (const float*)d_in[5];
    const float* b_ih  = (const float*)d_in[6];
    const float* w_hh  = (const float*)d_in[7];
    const float* b_hh  = (const float*)d_in[8];
    const float* w_me  = (const float*)d_in[9];
    const float* b_me  = (const float*)d_in[10];
    const float* w_md  = (const float*)d_in[11];
    const float* b_md  = (const float*)d_in[12];
    const float* s1_w1 = (const float*)d_in[13];
    const float* s1_b1 = (const float*)d_in[14];
    const float* s1_w2 = (const float*)d_in[15];
    const float* s1_b2 = (const float*)d_in[16];
    const float* s1_w3 = (const float*)d_in[17];
    const float* s1_b3 = (const float*)d_in[18];
    const float* s2_w1 = (const float*)d_in[19];
    const float* s2_b1 = (const float*)d_in[20];
    const float* s2_w2 = (const float*)d_in[21];
    const float* s2_b2 = (const float*)d_in[22];
    const float* s2_w3 = (const float*)d_in[23];
    const float* s2_b3 = (const float*)d_in[24];
    const float* g1_w  = (const float*)d_in[25];
    const float* g1_ai = (const float*)d_in[26];
    const float* g1_aj = (const float*)d_in[27];
    const float* g1_b  = (const float*)d_in[28];
    const float* g2_w  = (const float*)d_in[29];
    const float* g2_ai = (const float*)d_in[30];
    const float* g2_aj = (const float*)d_in[31];
    const float* g2_b  = (const float*)d_in[32];
    const float* w_v   = (const float*)d_in[33];
    const float* b_v   = (const float*)d_in[34];
    const float* w_a   = (const float*)d_in[35];
    const float* b_a   = (const float*)d_in[36];

    float* out = (float*)d_out;
    float* action = out;               // [1,256,10] = 2560
    float* value  = out + 2560;        // [256,1]
    float* h_new  = out + 2816;        // [256,256]
    float* c_new  = out + 68352;       // [256,256]

    float* ws = (float*)d_ws;
    float* comm  = ws;                 // 65536
    float* A1    = ws + 65536;         // 32768
    float* B1    = ws + 98304;         // 32768
    float* A2    = ws + 131072;        // 32768
    float* B2    = ws + 163840;        // 32768
    float* adj1  = ws + 196608;        // 65536
    float* adj2  = ws + 262144;        // 65536
    float* h1    = ws + 327680;        // 131072
    float* ci1   = ws + 458752;        // 1024
    float* cj1   = ws + 459776;        // 1024
    float* comm2 = ws + 460800;        // 131072
    float* h2    = ws + 591872;        // 65536
    float* ci2   = ws + 657408;        // 256
    float* cj2   = ws + 657664;        // 256
    float* out2  = ws + 657920;        // 65536
    float* comm3 = ws + 723456;        // 65536

    k_lstm<<<NA, 256, 0, stream>>>(obs, hs, cs, w_obs, b_obs, w_ih, b_ih, w_hh, b_hh,
                                   h_new, c_new);
    k_lin<<<NA, 256, 0, stream>>>(h_new, w_me, b_me, comm, 256, 256);

    // schedulers: A = comm@w1_top + b1, B = comm@w1_bot
    k_lin<<<NA, 256, 0, stream>>>(comm, s1_w1, s1_b1, A1, 256, 128);
    k_lin<<<NA, 256, 0, stream>>>(comm, s1_w1 + 256 * 128, nullptr, B1, 256, 128);
    k_lin<<<NA, 256, 0, stream>>>(comm, s2_w1, s2_b1, A2, 256, 128);
    k_lin<<<NA, 256, 0, stream>>>(comm, s2_w1 + 256 * 128, nullptr, B2, 256, 128);
    k_sched<<<NA, 256, 0, stream>>>(A1, B1, s1_w2, s1_b2, s1_w3, s1_b3, adj1, 1u);
    k_sched<<<NA, 256, 0, stream>>>(A2, B2, s2_w2, s2_b2, s2_w3, s2_b3, adj2, 2u);

    // GAT1
    k_lin<<<NA, 256, 0, stream>>>(comm, g1_w, nullptr, h1, 256, 512);
    k_attcoef<<<NA, 64, 0, stream>>>(h1, g1_ai, g1_aj, ci1, cj1, 4, 128);
    k_gat1<<<NA, 256, 0, stream>>>(h1, adj1, ci1, cj1, g1_b, comm2);

    // GAT2
    k_lin<<<NA, 256, 0, stream>>>(comm2, g2_w, nullptr, h2, 512, 256);
    k_attcoef<<<NA, 64, 0, stream>>>(h2, g2_ai, g2_aj, ci2, cj2, 1, 256);
    k_gat2<<<NA, 256, 0, stream>>>(h2, adj2, ci2, cj2, g2_b, out2);

    // decode + heads
    k_lin<<<NA, 256, 0, stream>>>(out2, w_md, b_md, comm3, 256, 256);
    k_head<<<NA, 64, 0, stream>>>(h_new, comm3, w_v, b_v, w_a, b_a, value, action);
}

// Round 2
// 348.418 us; speedup vs baseline: 1.2385x; 1.2385x over previous
//
#include <hip/hip_runtime.h>
#include <stdint.h>
#include <math.h>

#define NA 256
#define HIDD 256
#define OBSD 128

// ---------------- threefry2x32 (JAX-exact) ----------------
__device__ __forceinline__ uint32_t rotl32_(uint32_t v, int d) {
    return (v << d) | (v >> (32 - d));
}

__device__ uint32_t jax_random_bits(uint32_t key_lo, uint32_t flat) {
    uint32_t a, b;
    bool first;
    if (flat < 65536u) { a = flat; b = flat + 65536u; first = true; }
    else               { a = flat - 65536u; b = flat; first = false; }
    uint32_t ks0 = 0u, ks1 = key_lo, ks2 = 0u ^ key_lo ^ 0x1BD11BDAu;
    uint32_t x0 = a + ks0, x1 = b + ks1;
    const int r0[4] = {13, 15, 26, 6};
    const int r1[4] = {17, 29, 16, 24};
#define TF_R4(RS) { for (int rr = 0; rr < 4; ++rr) { x0 += x1; x1 = rotl32_(x1, RS[rr]); x1 ^= x0; } }
    TF_R4(r0); x0 += ks1; x1 += ks2 + 1u;
    TF_R4(r1); x0 += ks2; x1 += ks0 + 2u;
    TF_R4(r0); x0 += ks0; x1 += ks1 + 3u;
    TF_R4(r1); x0 += ks1; x1 += ks2 + 4u;
    TF_R4(r0); x0 += ks2; x1 += ks0 + 5u;
#undef TF_R4
    return first ? x0 : x1;
}

__device__ float jax_gumbel(uint32_t key_lo, uint32_t flat) {
    uint32_t bits = jax_random_bits(key_lo, flat);
    uint32_t v = (bits >> 9) | 0x3F800000u;
    float u = __uint_as_float(v) - 1.0f;
    u = u + 1e-10f;
    u = fmaxf(1e-10f, u);
    return -logf(-logf(u));
}

// ---------------- fused obs-proj + LSTM cell ----------------
// grid (64, 4): 4 rows per block, 64 gate-cols per block (all 4 gates for those cols)
__global__ void k_lstm(const float* __restrict__ obs, const float* __restrict__ hs,
                       const float* __restrict__ cs,
                       const float* __restrict__ w_obs, const float* __restrict__ b_obs,
                       const float* __restrict__ w_ih, const float* __restrict__ b_ih,
                       const float* __restrict__ w_hh, const float* __restrict__ b_hh,
                       float* __restrict__ h_out, float* __restrict__ c_out) {
    __shared__ float o_l[4][OBSD];
    __shared__ float x_l[4][HIDD];
    __shared__ float h_l[4][HIDD];
    __shared__ float red[4][4][4][64];   // [ks][row][gate][col]
    int r0 = blockIdx.x * 4;
    int c0 = blockIdx.y * 64;
    int t = threadIdx.x;
    for (int idx = t; idx < 4 * OBSD; idx += 256) {
        int r = idx >> 7, c = idx & 127;
        o_l[r][c] = obs[(r0 + r) * OBSD + c];
    }
    for (int idx = t; idx < 4 * HIDD; idx += 256) {
        int r = idx >> 8, c = idx & 255;
        h_l[r][c] = hs[(r0 + r) * HIDD + c];
    }
    __syncthreads();
    // x = obs @ w_obs + b_obs (all 256 cols, 4 rows)
    for (int idx = t; idx < 4 * HIDD; idx += 256) {
        int r = idx >> 8, c = idx & 255;
        float acc = b_obs[c];
        for (int k = 0; k < OBSD; ++k) acc += o_l[r][k] * w_obs[k * HIDD + c];
        x_l[r][c] = acc;
    }
    __syncthreads();
    int col = t & 63, ks = t >> 6;
    int gc = c0 + col;
    float acc[4][4];
#pragma unroll
    for (int r = 0; r < 4; ++r)
#pragma unroll
        for (int g = 0; g < 4; ++g) acc[r][g] = 0.f;
    for (int k = ks * 64; k < ks * 64 + 64; ++k) {
#pragma unroll
        for (int g = 0; g < 4; ++g) {
            float w = w_ih[k * 1024 + g * 256 + gc];
#pragma unroll
            for (int r = 0; r < 4; ++r) acc[r][g] += x_l[r][k] * w;
        }
    }
    for (int k = ks * 64; k < ks * 64 + 64; ++k) {
#pragma unroll
        for (int g = 0; g < 4; ++g) {
            float w = w_hh[k * 1024 + g * 256 + gc];
#pragma unroll
            for (int r = 0; r < 4; ++r) acc[r][g] += h_l[r][k] * w;
        }
    }
#pragma unroll
    for (int r = 0; r < 4; ++r)
#pragma unroll
        for (int g = 0; g < 4; ++g) red[ks][r][g][col] = acc[r][g];
    __syncthreads();
    {
        int r = t >> 6;   // 0..3
        int c = t & 63;
        int gcc = c0 + c;
        float gate[4];
#pragma unroll
        for (int g = 0; g < 4; ++g) {
            gate[g] = red[0][r][g][c] + red[1][r][g][c] + red[2][r][g][c] + red[3][r][g][c]
                    + b_ih[g * 256 + gcc] + b_hh[g * 256 + gcc];
        }
        float ig = 1.f / (1.f + expf(-gate[0]));
        float fg = 1.f / (1.f + expf(-gate[1]));
        float gg = tanhf(gate[2]);
        float og = 1.f / (1.f + expf(-gate[3]));
        float cn = fg * cs[(r0 + r) * HIDD + gcc] + ig * gg;
        float hn = og * tanhf(cn);
        h_out[(r0 + r) * HIDD + gcc] = hn;
        c_out[(r0 + r) * HIDD + gcc] = cn;
    }
}

// ---------------- linear: Y[i] = X[i] @ W (+ b); grid (rows, Nout/64) ----------------
__global__ void k_lin(const float* __restrict__ X, const float* __restrict__ W,
                      const float* __restrict__ b, float* __restrict__ Y,
                      int K, int Nout) {
    __shared__ float xr[512];
    __shared__ float red[4][64];
    int i = blockIdx.x, t = threadIdx.x;
    int n = blockIdx.y * 64 + (t & 63);
    int ks = t >> 6;
    for (int k = t; k < K; k += 256) xr[k] = X[i * K + k];
    __syncthreads();
    int kper = K >> 2;
    float acc = 0.f;
    for (int k = ks * kper; k < (ks + 1) * kper; ++k) acc += xr[k] * W[k * Nout + n];
    red[ks][t & 63] = acc;
    __syncthreads();
    if (ks == 0) {
        float r = red[0][t] + red[1][t] + red[2][t] + red[3][t];
        Y[i * Nout + n] = r + (b ? b[n] : 0.f);
    }
}

// ---------------- scheduler pairwise MLP + gumbel argmax -> adjacency ----------------
// grid (256, 8): i = bx, j in [by*32, by*32+32)
__global__ void k_sched(const float* __restrict__ A, const float* __restrict__ B,
                        const float* __restrict__ w2, const float* __restrict__ b2,
                        const float* __restrict__ w3, const float* __restrict__ b3,
                        float* __restrict__ adj, uint32_t key_lo) {
    __shared__ float a_l[128];
    __shared__ float w2_l[128 * 32];
    __shared__ float z1_l[8][128];
    __shared__ float b2_l[32];
    __shared__ float w3_l[64];
    __shared__ float b3_l[2];
    int i = blockIdx.x, t = threadIdx.x;
    int jbase = blockIdx.y * 32;
    if (t < 128) a_l[t] = A[i * 128 + t];
    for (int k = t; k < 4096; k += 256) w2_l[k] = w2[k];
    if (t < 32) b2_l[t] = b2[t];
    if (t < 64) w3_l[t] = w3[t];
    if (t < 2) b3_l[t] = b3[t];
    __syncthreads();
    int jj = t >> 5, k2 = t & 31;
    for (int j0 = jbase; j0 < jbase + 32; j0 += 8) {
        for (int idx = t; idx < 1024; idx += 256) {
            int jl = idx >> 7, k = idx & 127;
            float v = a_l[k] + B[(j0 + jl) * 128 + k];
            z1_l[jl][k] = v > 0.f ? v : 0.f;
        }
        __syncthreads();
        float acc = b2_l[k2];
        for (int k = 0; k < 128; ++k) acc += z1_l[jj][k] * w2_l[k * 32 + k2];
        acc = acc > 0.f ? acc : 0.f;
        float p0 = acc * w3_l[2 * k2], p1 = acc * w3_l[2 * k2 + 1];
        for (int off = 16; off; off >>= 1) {
            p0 += __shfl_xor(p0, off);
            p1 += __shfl_xor(p1, off);
        }
        if (k2 == 0) {
            int j = j0 + jj;
            float l0 = p0 + b3_l[0], l1 = p1 + b3_l[1];
            uint32_t flat = (uint32_t)(i * 256 + j) * 2u;
            float g0 = jax_gumbel(key_lo, flat);
            float g1 = jax_gumbel(key_lo, flat + 1u);
            adj[i * 256 + j] = (l1 + g1 > l0 + g0) ? 1.0f : 0.0f;
        }
        __syncthreads();
    }
}

// ---------------- GAT attention coefficients ci/cj ----------------
__global__ void k_attcoef(const float* __restrict__ H, const float* __restrict__ ai,
                          const float* __restrict__ aj, float* __restrict__ ci,
                          float* __restrict__ cj, int heads, int F) {
    int n = blockIdx.x, lane = threadIdx.x; // 64 threads
    for (int h = 0; h < heads; ++h) {
        float pi = 0.f, pj = 0.f;
        for (int f = lane; f < F; f += 64) {
            float v = H[n * heads * F + h * F + f];
            pi += v * ai[h * F + f];
            pj += v * aj[h * F + f];
        }
        for (int off = 32; off; off >>= 1) {
            pi += __shfl_xor(pi, off);
            pj += __shfl_xor(pj, off);
        }
        if (lane == 0) { ci[n * heads + h] = pi; cj[n * heads + h] = pj; }
    }
}

// ---------------- GAT layer 1 (4 heads, concat, +bias, elu); grid (256, 2) ----------------
__global__ void k_gat1(const float* __restrict__ H, const float* __restrict__ adj,
                       const float* __restrict__ ci, const float* __restrict__ cj,
                       const float* __restrict__ bias, float* __restrict__ out) {
    __shared__ float att[4][256];
    int i = blockIdx.x, t = threadIdx.x;
    float adjv = (t == i) ? 1.f : adj[i * 256 + t];
#pragma unroll
    for (int h = 0; h < 4; ++h) {
        float e = ci[i * 4 + h] + cj[t * 4 + h];
        e = e >= 0.f ? e : 0.2f * e;
        att[h][t] = adjv > 0.f ? e : -INFINITY;
    }
    __syncthreads();
    {
        int h = t >> 6, lane = t & 63;
        float m = -INFINITY;
        for (int j = lane; j < 256; j += 64) m = fmaxf(m, att[h][j]);
        for (int off = 32; off; off >>= 1) m = fmaxf(m, __shfl_xor(m, off));
        float vals[4];
        float s = 0.f;
#pragma unroll
        for (int r = 0; r < 4; ++r) {
            int j = lane + 64 * r;
            float v = expf(att[h][j] - m);
            vals[r] = v; s += v;
        }
        for (int off = 32; off; off >>= 1) s += __shfl_xor(s, off);
        float inv = 1.f / s;
#pragma unroll
        for (int r = 0; r < 4; ++r) { int j = lane + 64 * r; att[h][j] = vals[r] * inv; }
    }
    __syncthreads();
    {
        int o = blockIdx.y * 256 + t;   // 0..511
        int h = o >> 7, f = o & 127;
        float acc = 0.f;
        for (int j = 0; j < 256; ++j) acc += att[h][j] * H[j * 512 + h * 128 + f];
        acc += bias[o];
        out[i * 512 + o] = acc > 0.f ? acc : expm1f(acc);
    }
}

// ---------------- GAT layer 2 (1 head, +bias); grid (256, 2) ----------------
__global__ void k_gat2(const float* __restrict__ H, const float* __restrict__ adj,
                       const float* __restrict__ ci, const float* __restrict__ cj,
                       const float* __restrict__ bias, float* __restrict__ out) {
    __shared__ float att[256];
    __shared__ float red[256];
    int i = blockIdx.x, t = threadIdx.x;
    float adjv = (t == i) ? 1.f : adj[i * 256 + t];
    float e = ci[i] + cj[t];
    e = e >= 0.f ? e : 0.2f * e;
    att[t] = adjv > 0.f ? e : -INFINITY;
    __syncthreads();
    int lane = t & 63;
    float m = -INFINITY;
    for (int j = lane; j < 256; j += 64) m = fmaxf(m, att[j]);
    for (int off = 32; off; off >>= 1) m = fmaxf(m, __shfl_xor(m, off));
    float s = 0.f;
    for (int j = lane; j < 256; j += 64) s += expf(att[j] - m);
    for (int off = 32; off; off >>= 1) s += __shfl_xor(s, off);
    float inv = 1.f / s;
    float myval = expf(att[t] - m) * inv;
    __syncthreads();
    att[t] = myval;
    __syncthreads();
    int col = blockIdx.y * 128 + (t & 127);
    int js = t >> 7;
    float acc = 0.f;
    for (int j = js * 128; j < js * 128 + 128; ++j) acc += att[j] * H[j * 256 + col];
    red[t] = acc;
    __syncthreads();
    if (js == 0) out[i * 256 + col] = red[t] + red[t + 128] + bias[col];
}

// ---------------- value + action heads ----------------
__global__ void k_head(const float* __restrict__ h_new, const float* __restrict__ comm,
                       const float* __restrict__ w_v, const float* __restrict__ b_v,
                       const float* __restrict__ w_a, const float* __restrict__ b_a,
                       float* __restrict__ value, float* __restrict__ action) {
    int i = blockIdx.x, lane = threadIdx.x; // 64 threads
    float p = 0.f;
    for (int k = lane; k < 256; k += 64)
        p += h_new[i * 256 + k] * w_v[k] + comm[i * 256 + k] * w_v[256 + k];
    for (int off = 32; off; off >>= 1) p += __shfl_xor(p, off);
    if (lane == 0) value[i] = p + b_v[0];

    int o = lane & 15, ks = lane >> 4;   // 16 outputs x 4 K-splits of 128
    float acc = 0.f;
    if (o < 10) {
        for (int k = ks * 128; k < ks * 128 + 128; ++k) {
            float x = (k < 256) ? h_new[i * 256 + k] : comm[i * 256 + (k - 256)];
            acc += x * w_a[k * 10 + o];
        }
    }
    acc += __shfl_xor(acc, 16);
    acc += __shfl_xor(acc, 32);
    float logit = (o < 10) ? acc + b_a[o] : -INFINITY;
    float m = logit;
    for (int off = 8; off; off >>= 1) m = fmaxf(m, __shfl_xor(m, off));
    float ex = (o < 10) ? expf(logit - m) : 0.f;
    float s = ex;
    for (int off = 8; off; off >>= 1) s += __shfl_xor(s, off);
    if (ks == 0 && o < 10) action[i * 10 + o] = logit - m - logf(s);
}

extern "C" void kernel_launch(void* const* d_in, const int* in_sizes, int n_in,
                              void* d_out, int out_size, void* d_ws, size_t ws_size,
                              hipStream_t stream) {
    const float* obs   = (const float*)d_in[0];
    const float* hs    = (const float*)d_in[1];
    const float* cs    = (const float*)d_in[2];
    const float* w_obs = (const float*)d_in[3];
    const float* b_obs = (const float*)d_in[4];
    const float* w_ih  = (const float*)d_in[5];
    const float* b_ih  = (const float*)d_in[6];
    const float* w_hh  = (const float*)d_in[7];
    const float* b_hh  = (const float*)d_in[8];
    const float* w_me  = (const float*)d_in[9];
    const float* b_me  = (const float*)d_in[10];
    const float* w_md  = (const float*)d_in[11];
    const float* b_md  = (const float*)d_in[12];
    const float* s1_w1 = (const float*)d_in[13];
    const float* s1_b1 = (const float*)d_in[14];
    const float* s1_w2 = (const float*)d_in[15];
    const float* s1_b2 = (const float*)d_in[16];
    const float* s1_w3 = (const float*)d_in[17];
    const float* s1_b3 = (const float*)d_in[18];
    const float* s2_w1 = (const float*)d_in[19];
    const float* s2_b1 = (const float*)d_in[20];
    const float* s2_w2 = (const float*)d_in[21];
    const float* s2_b2 = (const float*)d_in[22];
    const float* s2_w3 = (const float*)d_in[23];
    const float* s2_b3 = (const float*)d_in[24];
    const float* g1_w  = (const float*)d_in[25];
    const float* g1_ai = (const float*)d_in[26];
    const float* g1_aj = (const float*)d_in[27];
    const float* g1_b  = (const float*)d_in[28];
    const float* g2_w  = (const float*)d_in[29];
    const float* g2_ai = (const float*)d_in[30];
    const float* g2_aj = (const float*)d_in[31];
    const float* g2_b  = (const float*)d_in[32];
    const float* w_v   = (const float*)d_in[33];
    const float* b_v   = (const float*)d_in[34];
    const float* w_a   = (const float*)d_in[35];
    const float* b_a   = (const float*)d_in[36];

    float* out = (float*)d_out;
    float* action = out;               // [1,256,10] = 2560
    float* value  = out + 2560;        // [256,1]
    float* h_new  = out + 2816;        // [256,256]
    float* c_new  = out + 68352;       // [256,256]

    float* ws = (float*)d_ws;
    float* comm  = ws;                 // 65536
    float* A1    = ws + 65536;         // 32768
    float* B1    = ws + 98304;         // 32768
    float* A2    = ws + 131072;        // 32768
    float* B2    = ws + 163840;        // 32768
    float* adj1  = ws + 196608;        // 65536
    float* adj2  = ws + 262144;        // 65536
    float* h1    = ws + 327680;        // 131072
    float* ci1   = ws + 458752;        // 1024
    float* cj1   = ws + 459776;        // 1024
    float* comm2 = ws + 460800;        // 131072
    float* h2    = ws + 591872;        // 65536
    float* ci2   = ws + 657408;        // 256
    float* cj2   = ws + 657664;        // 256
    float* out2  = ws + 657920;        // 65536
    float* comm3 = ws + 723456;        // 65536

    k_lstm<<<dim3(NA / 4, 4), 256, 0, stream>>>(obs, hs, cs, w_obs, b_obs,
                                                w_ih, b_ih, w_hh, b_hh, h_new, c_new);
    k_lin<<<dim3(NA, 4), 256, 0, stream>>>(h_new, w_me, b_me, comm, 256, 256);

    // schedulers: A = comm@w1_top + b1, B = comm@w1_bot
    k_lin<<<dim3(NA, 2), 256, 0, stream>>>(comm, s1_w1, s1_b1, A1, 256, 128);
    k_lin<<<dim3(NA, 2), 256, 0, stream>>>(comm, s1_w1 + 256 * 128, nullptr, B1, 256, 128);
    k_lin<<<dim3(NA, 2), 256, 0, stream>>>(comm, s2_w1, s2_b1, A2, 256, 128);
    k_lin<<<dim3(NA, 2), 256, 0, stream>>>(comm, s2_w1 + 256 * 128, nullptr, B2, 256, 128);
    k_sched<<<dim3(NA, 8), 256, 0, stream>>>(A1, B1, s1_w2, s1_b2, s1_w3, s1_b3, adj1, 1u);
    k_sched<<<dim3(NA, 8), 256, 0, stream>>>(A2, B2, s2_w2, s2_b2, s2_w3, s2_b3, adj2, 2u);

    // GAT1
    k_lin<<<dim3(NA, 8), 256, 0, stream>>>(comm, g1_w, nullptr, h1, 256, 512);
    k_attcoef<<<NA, 64, 0, stream>>>(h1, g1_ai, g1_aj, ci1, cj1, 4, 128);
    k_gat1<<<dim3(NA, 2), 256, 0, stream>>>(h1, adj1, ci1, cj1, g1_b, comm2);

    // GAT2
    k_lin<<<dim3(NA, 4), 256, 0, stream>>>(comm2, g2_w, nullptr, h2, 512, 256);
    k_attcoef<<<NA, 64, 0, stream>>>(h2, g2_ai, g2_aj, ci2, cj2, 1, 256);
    k_gat2<<<dim3(NA, 2), 256, 0, stream>>>(h2, adj2, ci2, cj2, g2_b, out2);

    // decode + heads
    k_lin<<<dim3(NA, 4), 256, 0, stream>>>(out2, w_md, b_md, comm3, 256, 256);
    k_head<<<NA, 64, 0, stream>>>(h_new, comm3, w_v, b_v, w_a, b_a, value, action);
}

// Round 3
// 163.877 us; speedup vs baseline: 2.6331x; 2.1261x over previous
//
#include <hip/hip_runtime.h>
#include <stdint.h>
#include <math.h>

#define NA 256
#define HIDD 256
#define OBSD 128

// ---------------- threefry2x32 (JAX-exact) ----------------
__device__ __forceinline__ uint32_t rotl32_(uint32_t v, int d) {
    return (v << d) | (v >> (32 - d));
}

__device__ uint32_t jax_random_bits(uint32_t key_lo, uint32_t flat) {
    uint32_t a, b;
    bool first;
    if (flat < 65536u) { a = flat; b = flat + 65536u; first = true; }
    else               { a = flat - 65536u; b = flat; first = false; }
    uint32_t ks0 = 0u, ks1 = key_lo, ks2 = 0u ^ key_lo ^ 0x1BD11BDAu;
    uint32_t x0 = a + ks0, x1 = b + ks1;
    const int r0[4] = {13, 15, 26, 6};
    const int r1[4] = {17, 29, 16, 24};
#define TF_R4(RS) { for (int rr = 0; rr < 4; ++rr) { x0 += x1; x1 = rotl32_(x1, RS[rr]); x1 ^= x0; } }
    TF_R4(r0); x0 += ks1; x1 += ks2 + 1u;
    TF_R4(r1); x0 += ks2; x1 += ks0 + 2u;
    TF_R4(r0); x0 += ks0; x1 += ks1 + 3u;
    TF_R4(r1); x0 += ks1; x1 += ks2 + 4u;
    TF_R4(r0); x0 += ks2; x1 += ks0 + 5u;
#undef TF_R4
    return first ? x0 : x1;
}

__device__ float jax_gumbel(uint32_t key_lo, uint32_t flat) {
    uint32_t bits = jax_random_bits(key_lo, flat);
    uint32_t v = (bits >> 9) | 0x3F800000u;
    float u = __uint_as_float(v) - 1.0f;
    u = u + 1e-10f;
    u = fmaxf(1e-10f, u);
    return -logf(-logf(u));
}

// ---------------- fused obs-proj + LSTM cell ----------------
// grid (64, 4): 4 rows per block, 64 gate-cols (per gate)
__global__ void k_lstm(const float* __restrict__ obs, const float* __restrict__ hs,
                       const float* __restrict__ cs,
                       const float* __restrict__ w_obs, const float* __restrict__ b_obs,
                       const float* __restrict__ w_ih, const float* __restrict__ b_ih,
                       const float* __restrict__ w_hh, const float* __restrict__ b_hh,
                       float* __restrict__ h_out, float* __restrict__ c_out) {
    __shared__ float o_l[4][OBSD];
    __shared__ float h_l[4][HIDD];
    __shared__ float x_l[4][HIDD];
    __shared__ float red[4][4][4][64];   // 16KB; also viewed as red2[16][256]
    int r0 = blockIdx.x * 4, c0 = blockIdx.y * 64, t = threadIdx.x;
    if (t < 128) ((float4*)o_l)[t] = ((const float4*)obs)[r0 * 32 + t];
    ((float4*)h_l)[t] = ((const float4*)hs)[r0 * 64 + t];
    __syncthreads();
    // obs proj -> x_l (4 rows x 256 cols)
    {
        int ks2 = t >> 6, c4o = t & 63;   // 4 k-splits x 64 col-quads
        float4 a0 = {0,0,0,0}, a1 = a0, a2 = a0, a3 = a0;
#pragma unroll
        for (int k = ks2 * 32; k < ks2 * 32 + 32; ++k) {
            float4 w = *(const float4*)(w_obs + k * HIDD + c4o * 4);
            float x0v = o_l[0][k], x1v = o_l[1][k], x2v = o_l[2][k], x3v = o_l[3][k];
            a0.x += x0v * w.x; a0.y += x0v * w.y; a0.z += x0v * w.z; a0.w += x0v * w.w;
            a1.x += x1v * w.x; a1.y += x1v * w.y; a1.z += x1v * w.z; a1.w += x1v * w.w;
            a2.x += x2v * w.x; a2.y += x2v * w.y; a2.z += x2v * w.z; a2.w += x2v * w.w;
            a3.x += x3v * w.x; a3.y += x3v * w.y; a3.z += x3v * w.z; a3.w += x3v * w.w;
        }
        float* red2 = (float*)red;        // [ks2*4+r][256]
        *(float4*)&red2[(ks2 * 4 + 0) * 256 + c4o * 4] = a0;
        *(float4*)&red2[(ks2 * 4 + 1) * 256 + c4o * 4] = a1;
        *(float4*)&red2[(ks2 * 4 + 2) * 256 + c4o * 4] = a2;
        *(float4*)&red2[(ks2 * 4 + 3) * 256 + c4o * 4] = a3;
        __syncthreads();
        int r = t >> 6, cg = t & 63;
        float* red2r = (float*)red;
        float4 s = ((const float4*)b_obs)[cg];
#pragma unroll
        for (int k2 = 0; k2 < 4; ++k2) {
            float4 v = *(const float4*)&red2r[(k2 * 4 + r) * 256 + cg * 4];
            s.x += v.x; s.y += v.y; s.z += v.z; s.w += v.w;
        }
        *(float4*)&x_l[r][cg * 4] = s;
    }
    __syncthreads();
    // gate GEMM: thread (ks = t>>4 in 0..15, c4 = t&15)
    int c4 = t & 15, ks = t >> 4;
    float4 acc[4][4];                     // [r][g]
#pragma unroll
    for (int r = 0; r < 4; ++r)
#pragma unroll
        for (int g = 0; g < 4; ++g) acc[r][g] = make_float4(0.f, 0.f, 0.f, 0.f);
#pragma unroll
    for (int k = ks * 16; k < ks * 16 + 16; ++k) {
#pragma unroll
        for (int g = 0; g < 4; ++g) {
            float4 w = *(const float4*)(w_ih + k * 1024 + g * 256 + c0 + c4 * 4);
#pragma unroll
            for (int r = 0; r < 4; ++r) {
                float xv = x_l[r][k];
                acc[r][g].x += xv * w.x; acc[r][g].y += xv * w.y;
                acc[r][g].z += xv * w.z; acc[r][g].w += xv * w.w;
            }
        }
    }
#pragma unroll
    for (int k = ks * 16; k < ks * 16 + 16; ++k) {
#pragma unroll
        for (int g = 0; g < 4; ++g) {
            float4 w = *(const float4*)(w_hh + k * 1024 + g * 256 + c0 + c4 * 4);
#pragma unroll
            for (int r = 0; r < 4; ++r) {
                float xv = h_l[r][k];
                acc[r][g].x += xv * w.x; acc[r][g].y += xv * w.y;
                acc[r][g].z += xv * w.z; acc[r][g].w += xv * w.w;
            }
        }
    }
    // reduce the 4 ks-per-wave via shuffle (lane>>4 = ks mod 4)
#pragma unroll
    for (int m = 16; m <= 32; m <<= 1) {
#pragma unroll
        for (int r = 0; r < 4; ++r)
#pragma unroll
            for (int g = 0; g < 4; ++g) {
                acc[r][g].x += __shfl_xor(acc[r][g].x, m);
                acc[r][g].y += __shfl_xor(acc[r][g].y, m);
                acc[r][g].z += __shfl_xor(acc[r][g].z, m);
                acc[r][g].w += __shfl_xor(acc[r][g].w, m);
            }
    }
    __syncthreads();                      // red reuse
    if (((t >> 4) & 3) == 0) {
        int wv = t >> 6;
#pragma unroll
        for (int r = 0; r < 4; ++r)
#pragma unroll
            for (int g = 0; g < 4; ++g)
                *(float4*)&red[wv][r][g][c4 * 4] = acc[r][g];
    }
    __syncthreads();
    {
        int r = t >> 6, c = t & 63;
        int gc = c0 + c;
        float gate[4];
#pragma unroll
        for (int g = 0; g < 4; ++g)
            gate[g] = red[0][r][g][c] + red[1][r][g][c] + red[2][r][g][c] + red[3][r][g][c]
                    + b_ih[g * 256 + gc] + b_hh[g * 256 + gc];
        float ig = 1.f / (1.f + expf(-gate[0]));
        float fg = 1.f / (1.f + expf(-gate[1]));
        float gg = tanhf(gate[2]);
        float og = 1.f / (1.f + expf(-gate[3]));
        float cn = fg * cs[(r0 + r) * HIDD + gc] + ig * gg;
        float hn = og * tanhf(cn);
        h_out[(r0 + r) * HIDD + gc] = hn;
        c_out[(r0 + r) * HIDD + gc] = cn;
    }
}

// ---------------- templated linear: grid (rows, NOUT/64), block 256 ----------------
template<int K, int NOUT>
__global__ void k_lin_t(const float* __restrict__ X, const float* __restrict__ W,
                        const float* __restrict__ b, float* __restrict__ Y) {
    constexpr int KS = 16;
    constexpr int KPER = K / KS;
    __shared__ float xr[K];
    __shared__ float red[KS][64];
    int i = blockIdx.x, t = threadIdx.x;
    int col0 = blockIdx.y * 64;
    for (int q = t; q < K / 4; q += 256) ((float4*)xr)[q] = ((const float4*)(X + i * K))[q];
    __syncthreads();
    int c4 = t & 15, ks = t >> 4;
    float4 acc = {0.f, 0.f, 0.f, 0.f};
#pragma unroll
    for (int k = ks * KPER; k < ks * KPER + KPER; ++k) {
        float4 w = *(const float4*)(W + k * NOUT + col0 + c4 * 4);
        float xv = xr[k];
        acc.x += xv * w.x; acc.y += xv * w.y; acc.z += xv * w.z; acc.w += xv * w.w;
    }
    *(float4*)&red[ks][c4 * 4] = acc;
    __syncthreads();
    if (t < 64) {
        float s = b ? b[col0 + t] : 0.f;
#pragma unroll
        for (int s2 = 0; s2 < KS; ++s2) s += red[s2][t];
        Y[i * NOUT + col0 + t] = s;
    }
}

// ---------------- fused A/B projections for both schedulers ----------------
// grid (256, 8): y bits: [2]=scheduler, [1]=A(0)/B(1), [0]=col half
__global__ void k_ab(const float* __restrict__ comm,
                     const float* __restrict__ s1w1, const float* __restrict__ s1b1,
                     const float* __restrict__ s2w1, const float* __restrict__ s2b1,
                     float* __restrict__ A1, float* __restrict__ B1,
                     float* __restrict__ A2, float* __restrict__ B2) {
    int y = blockIdx.y;
    int sel = y >> 2, part = (y >> 1) & 1, half = y & 1;
    const float* W = (sel ? s2w1 : s1w1) + part * 256 * 128 + half * 64;
    const float* bias = part ? nullptr : ((sel ? s2b1 : s1b1) + half * 64);
    float* Y = sel ? (part ? B2 : A2) : (part ? B1 : A1);
    __shared__ float xr[256];
    __shared__ float red[16][64];
    int i = blockIdx.x, t = threadIdx.x;
    if (t < 64) ((float4*)xr)[t] = ((const float4*)(comm + i * 256))[t];
    __syncthreads();
    int c4 = t & 15, ks = t >> 4;
    float4 acc = {0.f, 0.f, 0.f, 0.f};
#pragma unroll
    for (int k = ks * 16; k < ks * 16 + 16; ++k) {
        float4 w = *(const float4*)(W + k * 128 + c4 * 4);
        float xv = xr[k];
        acc.x += xv * w.x; acc.y += xv * w.y; acc.z += xv * w.z; acc.w += xv * w.w;
    }
    *(float4*)&red[ks][c4 * 4] = acc;
    __syncthreads();
    if (t < 64) {
        float s = bias ? bias[t] : 0.f;
#pragma unroll
        for (int s2 = 0; s2 < 16; ++s2) s += red[s2][t];
        Y[i * 128 + half * 64 + t] = s;
    }
}

// ---------------- scheduler pairwise MLP + gumbel argmax -> adjacency ----------------
// grid (256, 16): i = bx, j in [by*16, by*16+16)
__global__ void k_sched(const float* __restrict__ A, const float* __restrict__ B,
                        const float* __restrict__ w2, const float* __restrict__ b2,
                        const float* __restrict__ w3, const float* __restrict__ b3,
                        float* __restrict__ adj, uint32_t key_lo) {
    __shared__ float4 w2t4[32 * 33];   // [c][33 quads], row stride 132 floats (16B-aligned, quad-bank spread)
    __shared__ float4 z1v4[8][32];
    __shared__ float4 a4[32];
    __shared__ float b2_l[32];
    __shared__ float w3_l[64];
    __shared__ float b3_l[2];
    int i = blockIdx.x, t = threadIdx.x;
    int jbase = blockIdx.y * 16;
    if (t < 32) a4[t] = ((const float4*)(A + i * 128))[t];
    if (t < 32) b2_l[t] = b2[t];
    if (t < 64) w3_l[t] = w3[t];
    if (t < 2)  b3_l[t] = b3[t];
    {   // transpose w2 [128][32] -> LDS [32][132]
        float* w2tf = (float*)w2t4;
        for (int q = t; q < 1024; q += 256) {
            int k = q >> 3, c4i = q & 7;
            float4 v = ((const float4*)w2)[q];
            w2tf[(c4i * 4 + 0) * 132 + k] = v.x;
            w2tf[(c4i * 4 + 1) * 132 + k] = v.y;
            w2tf[(c4i * 4 + 2) * 132 + k] = v.z;
            w2tf[(c4i * 4 + 3) * 132 + k] = v.w;
        }
    }
    __syncthreads();
    int jj = t >> 5, c = t & 31;
    for (int j0 = jbase; j0 < jbase + 16; j0 += 8) {
        {
            float4 av = a4[c];
            float4 bv = ((const float4*)(B + (j0 + jj) * 128))[c];
            float4 z;
            z.x = fmaxf(av.x + bv.x, 0.f);
            z.y = fmaxf(av.y + bv.y, 0.f);
            z.z = fmaxf(av.z + bv.z, 0.f);
            z.w = fmaxf(av.w + bv.w, 0.f);
            z1v4[jj][c] = z;
        }
        __syncthreads();
        float acc = b2_l[c];
#pragma unroll
        for (int k4 = 0; k4 < 32; ++k4) {
            float4 z = z1v4[jj][k4];
            float4 w = w2t4[c * 33 + k4];
            acc += z.x * w.x + z.y * w.y + z.z * w.z + z.w * w.w;
        }
        acc = fmaxf(acc, 0.f);
        float p0 = acc * w3_l[2 * c], p1 = acc * w3_l[2 * c + 1];
#pragma unroll
        for (int off = 16; off; off >>= 1) {
            p0 += __shfl_xor(p0, off);
            p1 += __shfl_xor(p1, off);
        }
        if (c < 2) {
            int j = j0 + jj;
            uint32_t flat = (uint32_t)(i * 256 + j) * 2u + (uint32_t)c;
            float l = (c == 0) ? (p0 + b3_l[0]) : (p1 + b3_l[1]);
            float v = l + jax_gumbel(key_lo, flat);
            float other = __shfl_xor(v, 1);
            if (c == 0) adj[i * 256 + j] = (other > v) ? 1.0f : 0.0f;
        }
        __syncthreads();
    }
}

// ---------------- GAT attention coefficients ci/cj ----------------
__global__ void k_attcoef(const float* __restrict__ H, const float* __restrict__ ai,
                          const float* __restrict__ aj, float* __restrict__ ci,
                          float* __restrict__ cj, int heads, int F) {
    int n = blockIdx.x, lane = threadIdx.x; // 64 threads
    for (int h = 0; h < heads; ++h) {
        float pi = 0.f, pj = 0.f;
        for (int f = lane; f < F; f += 64) {
            float v = H[n * heads * F + h * F + f];
            pi += v * ai[h * F + f];
            pj += v * aj[h * F + f];
        }
        for (int off = 32; off; off >>= 1) {
            pi += __shfl_xor(pi, off);
            pj += __shfl_xor(pj, off);
        }
        if (lane == 0) { ci[n * heads + h] = pi; cj[n * heads + h] = pj; }
    }
}

// ---------------- GAT layer 1 (4 heads, concat, +bias, elu); grid (256, 2) ----------------
__global__ void k_gat1(const float* __restrict__ H, const float* __restrict__ adj,
                       const float* __restrict__ ci, const float* __restrict__ cj,
                       const float* __restrict__ bias, float* __restrict__ out) {
    __shared__ float att[4][256];
    __shared__ float red[4][256];
    int i = blockIdx.x, t = threadIdx.x;
    float adjv = (t == i) ? 1.f : adj[i * 256 + t];
#pragma unroll
    for (int h = 0; h < 4; ++h) {
        float e = ci[i * 4 + h] + cj[t * 4 + h];
        e = e >= 0.f ? e : 0.2f * e;
        att[h][t] = adjv > 0.f ? e : -INFINITY;
    }
    __syncthreads();
    {
        int h = t >> 6, lane = t & 63;
        float m = -INFINITY;
        for (int j = lane; j < 256; j += 64) m = fmaxf(m, att[h][j]);
        for (int off = 32; off; off >>= 1) m = fmaxf(m, __shfl_xor(m, off));
        float vals[4], s = 0.f;
#pragma unroll
        for (int r = 0; r < 4; ++r) {
            float v = expf(att[h][lane + 64 * r] - m);
            vals[r] = v; s += v;
        }
        for (int off = 32; off; off >>= 1) s += __shfl_xor(s, off);
        float inv = 1.f / s;
#pragma unroll
        for (int r = 0; r < 4; ++r) att[h][lane + 64 * r] = vals[r] * inv;
    }
    __syncthreads();
    {
        int js = t >> 6, o4 = t & 63;
        int o = blockIdx.y * 256 + o4 * 4;     // global col
        int h = o >> 7;
        const float* ah = att[h];
        float4 acc = {0.f, 0.f, 0.f, 0.f};
#pragma unroll
        for (int j = js * 64; j < js * 64 + 64; ++j) {
            float4 hv = *(const float4*)(H + j * 512 + o);
            float av = ah[j];
            acc.x += av * hv.x; acc.y += av * hv.y; acc.z += av * hv.z; acc.w += av * hv.w;
        }
        *(float4*)&red[js][o4 * 4] = acc;
    }
    __syncthreads();
    {
        int o = blockIdx.y * 256 + t;
        float s = red[0][t] + red[1][t] + red[2][t] + red[3][t] + bias[o];
        out[i * 512 + o] = s > 0.f ? s : expm1f(s);
    }
}

// ---------------- GAT layer 2 (1 head, +bias); grid (256, 2) ----------------
__global__ void k_gat2(const float* __restrict__ H, const float* __restrict__ adj,
                       const float* __restrict__ ci, const float* __restrict__ cj,
                       const float* __restrict__ bias, float* __restrict__ out) {
    __shared__ float att[256];
    __shared__ float red[8][128];
    int i = blockIdx.x, t = threadIdx.x;
    float adjv = (t == i) ? 1.f : adj[i * 256 + t];
    float e = ci[i] + cj[t];
    e = e >= 0.f ? e : 0.2f * e;
    att[t] = adjv > 0.f ? e : -INFINITY;
    __syncthreads();
    int lane = t & 63;
    float m = -INFINITY;
    for (int j = lane; j < 256; j += 64) m = fmaxf(m, att[j]);
    for (int off = 32; off; off >>= 1) m = fmaxf(m, __shfl_xor(m, off));
    float s = 0.f;
    for (int j = lane; j < 256; j += 64) s += expf(att[j] - m);
    for (int off = 32; off; off >>= 1) s += __shfl_xor(s, off);
    float inv = 1.f / s;
    float myval = expf(att[t] - m) * inv;
    __syncthreads();
    att[t] = myval;
    __syncthreads();
    {
        int js = t >> 5, o4 = t & 31;
        int o = blockIdx.y * 128 + o4 * 4;
        float4 acc = {0.f, 0.f, 0.f, 0.f};
#pragma unroll
        for (int j = js * 32; j < js * 32 + 32; ++j) {
            float4 hv = *(const float4*)(H + j * 256 + o);
            float av = att[j];
            acc.x += av * hv.x; acc.y += av * hv.y; acc.z += av * hv.z; acc.w += av * hv.w;
        }
        *(float4*)&red[js][o4 * 4] = acc;
    }
    __syncthreads();
    if (t < 128) {
        int o = blockIdx.y * 128 + t;
        float s2 = bias[o];
#pragma unroll
        for (int k2 = 0; k2 < 8; ++k2) s2 += red[k2][t];
        out[i * 256 + o] = s2;
    }
}

// ---------------- value + action heads ----------------
__global__ void k_head(const float* __restrict__ h_new, const float* __restrict__ comm,
                       const float* __restrict__ w_v, const float* __restrict__ b_v,
                       const float* __restrict__ w_a, const float* __restrict__ b_a,
                       float* __restrict__ value, float* __restrict__ action) {
    int i = blockIdx.x, lane = threadIdx.x; // 64 threads
    float p = 0.f;
    for (int k = lane; k < 256; k += 64)
        p += h_new[i * 256 + k] * w_v[k] + comm[i * 256 + k] * w_v[256 + k];
    for (int off = 32; off; off >>= 1) p += __shfl_xor(p, off);
    if (lane == 0) value[i] = p + b_v[0];

    int o = lane & 15, ks = lane >> 4;   // 16 outputs x 4 K-splits of 128
    float acc = 0.f;
    if (o < 10) {
        for (int k = ks * 128; k < ks * 128 + 128; ++k) {
            float x = (k < 256) ? h_new[i * 256 + k] : comm[i * 256 + (k - 256)];
            acc += x * w_a[k * 10 + o];
        }
    }
    acc += __shfl_xor(acc, 16);
    acc += __shfl_xor(acc, 32);
    float logit = (o < 10) ? acc + b_a[o] : -INFINITY;
    float m = logit;
    for (int off = 8; off; off >>= 1) m = fmaxf(m, __shfl_xor(m, off));
    float ex = (o < 10) ? expf(logit - m) : 0.f;
    float s = ex;
    for (int off = 8; off; off >>= 1) s += __shfl_xor(s, off);
    if (ks == 0 && o < 10) action[i * 10 + o] = logit - m - logf(s);
}

extern "C" void kernel_launch(void* const* d_in, const int* in_sizes, int n_in,
                              void* d_out, int out_size, void* d_ws, size_t ws_size,
                              hipStream_t stream) {
    const float* obs   = (const float*)d_in[0];
    const float* hs    = (const float*)d_in[1];
    const float* cs    = (const float*)d_in[2];
    const float* w_obs = (const float*)d_in[3];
    const float* b_obs = (const float*)d_in[4];
    const float* w_ih  = (const float*)d_in[5];
    const float* b_ih  = (const float*)d_in[6];
    const float* w_hh  = (const float*)d_in[7];
    const float* b_hh  = (const float*)d_in[8];
    const float* w_me  = (const float*)d_in[9];
    const float* b_me  = (const float*)d_in[10];
    const float* w_md  = (const float*)d_in[11];
    const float* b_md  = (const float*)d_in[12];
    const float* s1_w1 = (const float*)d_in[13];
    const float* s1_b1 = (const float*)d_in[14];
    const float* s1_w2 = (const float*)d_in[15];
    const float* s1_b2 = (const float*)d_in[16];
    const float* s1_w3 = (const float*)d_in[17];
    const float* s1_b3 = (const float*)d_in[18];
    const float* s2_w1 = (const float*)d_in[19];
    const float* s2_b1 = (const float*)d_in[20];
    const float* s2_w2 = (const float*)d_in[21];
    const float* s2_b2 = (const float*)d_in[22];
    const float* s2_w3 = (const float*)d_in[23];
    const float* s2_b3 = (const float*)d_in[24];
    const float* g1_w  = (const float*)d_in[25];
    const float* g1_ai = (const float*)d_in[26];
    const float* g1_aj = (const float*)d_in[27];
    const float* g1_b  = (const float*)d_in[28];
    const float* g2_w  = (const float*)d_in[29];
    const float* g2_ai = (const float*)d_in[30];
    const float* g2_aj = (const float*)d_in[31];
    const float* g2_b  = (const float*)d_in[32];
    const float* w_v   = (const float*)d_in[33];
    const float* b_v   = (const float*)d_in[34];
    const float* w_a   = (const float*)d_in[35];
    const float* b_a   = (const float*)d_in[36];

    float* out = (float*)d_out;
    float* action = out;               // [1,256,10] = 2560
    float* value  = out + 2560;        // [256,1]
    float* h_new  = out + 2816;        // [256,256]
    float* c_new  = out + 68352;       // [256,256]

    float* ws = (float*)d_ws;
    float* comm  = ws;                 // 65536
    float* A1    = ws + 65536;         // 32768
    float* B1    = ws + 98304;         // 32768
    float* A2    = ws + 131072;        // 32768
    float* B2    = ws + 163840;        // 32768
    float* adj1  = ws + 196608;        // 65536
    float* adj2  = ws + 262144;        // 65536
    float* h1    = ws + 327680;        // 131072
    float* ci1   = ws + 458752;        // 1024
    float* cj1   = ws + 459776;        // 1024
    float* comm2 = ws + 460800;        // 131072
    float* h2    = ws + 591872;        // 65536
    float* ci2   = ws + 657408;        // 256
    float* cj2   = ws + 657664;        // 256
    float* out2  = ws + 657920;        // 65536
    float* comm3 = ws + 723456;        // 65536

    k_lstm<<<dim3(64, 4), 256, 0, stream>>>(obs, hs, cs, w_obs, b_obs,
                                            w_ih, b_ih, w_hh, b_hh, h_new, c_new);
    k_lin_t<256, 256><<<dim3(NA, 4), 256, 0, stream>>>(h_new, w_me, b_me, comm);

    k_ab<<<dim3(NA, 8), 256, 0, stream>>>(comm, s1_w1, s1_b1, s2_w1, s2_b1,
                                          A1, B1, A2, B2);
    k_sched<<<dim3(NA, 16), 256, 0, stream>>>(A1, B1, s1_w2, s1_b2, s1_w3, s1_b3, adj1, 1u);
    k_sched<<<dim3(NA, 16), 256, 0, stream>>>(A2, B2, s2_w2, s2_b2, s2_w3, s2_b3, adj2, 2u);

    // GAT1
    k_lin_t<256, 512><<<dim3(NA, 8), 256, 0, stream>>>(comm, g1_w, nullptr, h1);
    k_attcoef<<<NA, 64, 0, stream>>>(h1, g1_ai, g1_aj, ci1, cj1, 4, 128);
    k_gat1<<<dim3(NA, 2), 256, 0, stream>>>(h1, adj1, ci1, cj1, g1_b, comm2);

    // GAT2
    k_lin_t<512, 256><<<dim3(NA, 4), 256, 0, stream>>>(comm2, g2_w, nullptr, h2);
    k_attcoef<<<NA, 64, 0, stream>>>(h2, g2_ai, g2_aj, ci2, cj2, 1, 256);
    k_gat2<<<dim3(NA, 2), 256, 0, stream>>>(h2, adj2, ci2, cj2, g2_b, out2);

    // decode + heads
    k_lin_t<256, 256><<<dim3(NA, 4), 256, 0, stream>>>(out2, w_md, b_md, comm3);
    k_head<<<NA, 64, 0, stream>>>(h_new, comm3, w_v, b_v, w_a, b_a, value, action);
}

// Round 4
// 95.967 us; speedup vs baseline: 4.4964x; 1.7076x over previous
//
#include <hip/hip_runtime.h>
#include <stdint.h>
#include <math.h>

#define NA 256

typedef __attribute__((ext_vector_type(4))) float f32x4;
typedef __attribute__((ext_vector_type(8))) short bfrag;   // 8 bf16 (4 VGPRs)
typedef __attribute__((ext_vector_type(4))) float cfrag;   // MFMA accum

// ---------------- threefry2x32 (JAX-exact) ----------------
__device__ __forceinline__ uint32_t rotl32_(uint32_t v, int d) {
    return (v << d) | (v >> (32 - d));
}

__device__ uint32_t jax_random_bits(uint32_t key_lo, uint32_t flat) {
    uint32_t a, b;
    bool first;
    if (flat < 65536u) { a = flat; b = flat + 65536u; first = true; }
    else               { a = flat - 65536u; b = flat; first = false; }
    uint32_t ks0 = 0u, ks1 = key_lo, ks2 = 0u ^ key_lo ^ 0x1BD11BDAu;
    uint32_t x0 = a + ks0, x1 = b + ks1;
    const int r0[4] = {13, 15, 26, 6};
    const int r1[4] = {17, 29, 16, 24};
#define TF_R4(RS) { for (int rr = 0; rr < 4; ++rr) { x0 += x1; x1 = rotl32_(x1, RS[rr]); x1 ^= x0; } }
    TF_R4(r0); x0 += ks1; x1 += ks2 + 1u;
    TF_R4(r1); x0 += ks2; x1 += ks0 + 2u;
    TF_R4(r0); x0 += ks0; x1 += ks1 + 3u;
    TF_R4(r1); x0 += ks1; x1 += ks2 + 4u;
    TF_R4(r0); x0 += ks2; x1 += ks0 + 5u;
#undef TF_R4
    return first ? x0 : x1;
}

__device__ float jax_gumbel(uint32_t key_lo, uint32_t flat) {
    uint32_t bits = jax_random_bits(key_lo, flat);
    uint32_t v = (bits >> 9) | 0x3F800000u;
    float u = __uint_as_float(v) - 1.0f;
    u = u + 1e-10f;
    u = fmaxf(1e-10f, u);
    return -logf(-logf(u));
}

__device__ __forceinline__ uint32_t f2bf(float f) {   // RNE f32->bf16 bits
    uint32_t u = __float_as_uint(f);
    return (u + 0x7FFFu + ((u >> 16) & 1u)) >> 16;
}

// ---------------- fused obs-proj + LSTM cell ----------------
// grid (32, 8): 8 rows, 32 hid-cols (=128 gate-cols) per block
__global__ __launch_bounds__(256) void k_lstm(
        const float* __restrict__ obs, const float* __restrict__ hs,
        const float* __restrict__ cs,
        const float* __restrict__ w_obs, const float* __restrict__ b_obs,
        const float* __restrict__ w_ih, const float* __restrict__ b_ih,
        const float* __restrict__ w_hh, const float* __restrict__ b_hh,
        float* __restrict__ h_out, float* __restrict__ c_out) {
    __shared__ float o_l[8][128];
    __shared__ float h_l[8][256];
    __shared__ float x_l[8][256];
    __shared__ float red[8192];            // 32KB, reused by both phases
    int r0 = blockIdx.x * 8, c0 = blockIdx.y * 32, t = threadIdx.x;
    ((f32x4*)o_l)[t] = ((const f32x4*)(obs + r0 * 128))[t];
    ((f32x4*)h_l)[t] = ((const f32x4*)(hs + r0 * 256))[t];
    ((f32x4*)h_l)[t + 256] = ((const f32x4*)(hs + r0 * 256))[t + 256];
    __syncthreads();
    // obs proj: x = obs @ w_obs + b_obs  (8 rows x 256 cols)
    {
        int ks = t >> 6, q = t & 63;       // 4 k-splits x 64 col-quads
        f32x4 acc[8];
#pragma unroll
        for (int r = 0; r < 8; ++r) acc[r] = (f32x4){0.f, 0.f, 0.f, 0.f};
#pragma unroll
        for (int k = ks * 32; k < ks * 32 + 32; ++k) {
            f32x4 w = *(const f32x4*)(w_obs + k * 256 + q * 4);
#pragma unroll
            for (int r = 0; r < 8; ++r) {
                float xv = o_l[r][k];
                acc[r].x += xv * w.x; acc[r].y += xv * w.y;
                acc[r].z += xv * w.z; acc[r].w += xv * w.w;
            }
        }
#pragma unroll
        for (int r = 0; r < 8; ++r)
            *(f32x4*)&red[(ks * 8 + r) * 256 + q * 4] = acc[r];
    }
    __syncthreads();
    {
#pragma unroll
        for (int rep = 0; rep < 8; ++rep) {
            int o = t + rep * 256;
            int r = o >> 8, c = o & 255;
            float s = b_obs[c];
#pragma unroll
            for (int k2 = 0; k2 < 4; ++k2) s += red[(k2 * 8 + r) * 256 + c];
            x_l[r][c] = s;
        }
    }
    __syncthreads();
    // gates: [8 rows] x [4 gates x 32 hid-cols], K = 512 (x:256, h:256)
    {
        int ks = t >> 5, cg = t & 31;      // 8 k-splits x (4 gates x 8 quads)
        int g = cg >> 3, qd = cg & 7;
        int col = g * 256 + c0 + qd * 4;
        const float* W = (ks < 4) ? w_ih : w_hh;
        const float* xl = (ks < 4) ? &x_l[0][0] : &h_l[0][0];
        int kb = (ks & 3) * 64;
        f32x4 acc[8];
#pragma unroll
        for (int r = 0; r < 8; ++r) acc[r] = (f32x4){0.f, 0.f, 0.f, 0.f};
#pragma unroll
        for (int kk = 0; kk < 64; ++kk) {
            int k = kb + kk;
            f32x4 w = *(const f32x4*)(W + k * 1024 + col);
#pragma unroll
            for (int r = 0; r < 8; ++r) {
                float xv = xl[r * 256 + k];
                acc[r].x += xv * w.x; acc[r].y += xv * w.y;
                acc[r].z += xv * w.z; acc[r].w += xv * w.w;
            }
        }
        __syncthreads();                   // red reuse safe
#pragma unroll
        for (int r = 0; r < 8; ++r)
            *(f32x4*)&red[(ks * 8 + r) * 128 + cg * 4] = acc[r];
    }
    __syncthreads();
    {
        int r = t >> 5, hc = t & 31;
        int gc = c0 + hc;
        float gate[4];
#pragma unroll
        for (int g = 0; g < 4; ++g) {
            float s = b_ih[g * 256 + gc] + b_hh[g * 256 + gc];
#pragma unroll
            for (int ks = 0; ks < 8; ++ks) s += red[(ks * 8 + r) * 128 + g * 32 + hc];
            gate[g] = s;
        }
        float ig = 1.f / (1.f + expf(-gate[0]));
        float fg = 1.f / (1.f + expf(-gate[1]));
        float gg = tanhf(gate[2]);
        float og = 1.f / (1.f + expf(-gate[3]));
        float cn = fg * cs[(r0 + r) * 256 + gc] + ig * gg;
        float hn = og * tanhf(cn);
        h_out[(r0 + r) * 256 + gc] = hn;
        c_out[(r0 + r) * 256 + gc] = cn;
    }
}

// ---------------- generic 8-row x 64-col GEMM tile ----------------
template<int K>
__device__ __forceinline__ void gemm_core(const float* __restrict__ X, int xs, int r0,
                                          const float* __restrict__ W, int ws,
                                          const float* __restrict__ bias,
                                          float* __restrict__ Y, int ys, int t,
                                          float* xr, float* red) {
    constexpr int KQ = K / 4;
#pragma unroll
    for (int q = t; q < 2 * K; q += 256) {
        int r = q / KQ, c = q % KQ;
        ((f32x4*)xr)[r * KQ + c] = ((const f32x4*)(X + (r0 + r) * xs))[c];
    }
    __syncthreads();
    constexpr int KP = K / 16;
    int qd = t & 15, ks = t >> 4;
    f32x4 acc[8];
#pragma unroll
    for (int r = 0; r < 8; ++r) acc[r] = (f32x4){0.f, 0.f, 0.f, 0.f};
#pragma unroll
    for (int k = ks * KP; k < ks * KP + KP; ++k) {
        f32x4 w = *(const f32x4*)(W + k * ws + qd * 4);
#pragma unroll
        for (int r = 0; r < 8; ++r) {
            float xv = xr[r * K + k];
            acc[r].x += xv * w.x; acc[r].y += xv * w.y;
            acc[r].z += xv * w.z; acc[r].w += xv * w.w;
        }
    }
#pragma unroll
    for (int r = 0; r < 8; ++r)
        *(f32x4*)&red[(ks * 8 + r) * 64 + qd * 4] = acc[r];
    __syncthreads();
#pragma unroll
    for (int rep = 0; rep < 2; ++rep) {
        int o = t + rep * 256;
        int r = o >> 6, c = o & 63;
        float s = bias ? bias[c] : 0.f;
#pragma unroll
        for (int ks2 = 0; ks2 < 16; ++ks2) s += red[(ks2 * 8 + r) * 64 + c];
        Y[(r0 + r) * ys + c] = s;
    }
}

template<int K>
__global__ __launch_bounds__(256) void k_gemm(const float* __restrict__ X, int xs,
                                              const float* __restrict__ W, int ws,
                                              const float* __restrict__ bias,
                                              float* __restrict__ Y, int ys) {
    __shared__ float xr[8 * K];
    __shared__ float red[16 * 8 * 64];
    int cb = blockIdx.y * 64;
    gemm_core<K>(X, xs, blockIdx.x * 8, W + cb, ws, bias ? bias + cb : nullptr,
                 Y + cb, ys, threadIdx.x, xr, red);
}

// multi-target GEMM from comm: y<8 -> h1 slices; y>=8 -> A1,B1,A2,B2 halves
__global__ __launch_bounds__(256) void k_mgemm(const float* __restrict__ comm,
        const float* __restrict__ g1_w,
        const float* __restrict__ s1w1, const float* __restrict__ s1b1,
        const float* __restrict__ s2w1, const float* __restrict__ s2b1,
        float* __restrict__ h1, float* __restrict__ A1, float* __restrict__ B1,
        float* __restrict__ A2, float* __restrict__ B2) {
    __shared__ float xr[8 * 256];
    __shared__ float red[16 * 8 * 64];
    int y = blockIdx.y;
    const float* W; int ws; const float* bias; float* Y; int ys;
    if (y < 8) {
        W = g1_w + y * 64; ws = 512; bias = nullptr; Y = h1 + y * 64; ys = 512;
    } else {
        int idx = y - 8;
        int sel = idx >> 2, part = (idx >> 1) & 1, half = idx & 1;
        W = (sel ? s2w1 : s1w1) + part * (256 * 128) + half * 64; ws = 128;
        bias = part ? nullptr : ((sel ? s2b1 : s1b1) + half * 64);
        float* tgt = sel ? (part ? B2 : A2) : (part ? B1 : A1);
        Y = tgt + half * 64; ys = 128;
    }
    gemm_core<256>(comm, 256, blockIdx.x * 8, W, ws, bias, Y, ys, threadIdx.x, xr, red);
}

// ---------------- scheduler: z1(bf16,LDS) -> MFMA z2 -> logits -> gumbel argmax ----------------
// grid (256, 2): block = (agent i, scheduler s)
__global__ __launch_bounds__(256) void k_sched(
        const float* __restrict__ A1, const float* __restrict__ B1,
        const float* __restrict__ s1w2, const float* __restrict__ s1b2,
        const float* __restrict__ s1w3, const float* __restrict__ s1b3,
        const float* __restrict__ A2, const float* __restrict__ B2,
        const float* __restrict__ s2w2, const float* __restrict__ s2b2,
        const float* __restrict__ s2w3, const float* __restrict__ s2b3,
        float* __restrict__ adj1, float* __restrict__ adj2) {
    __shared__ __align__(16) char z1z2[65536];   // z1 bf16 [256][128] swz | z2 f32 [256][36]
    __shared__ __align__(16) char w2l[8192];     // w2^T bf16 [32][128] swz
    __shared__ float a_l[128];
    __shared__ float b2_l[32], w3_l[64], b3_l[2];
    int i = blockIdx.x, t = threadIdx.x, s = blockIdx.y;
    const float* A  = s ? A2 : A1;
    const float* B  = s ? B2 : B1;
    const float* w2 = s ? s2w2 : s1w2;
    const float* b2 = s ? s2b2 : s1b2;
    const float* w3 = s ? s2w3 : s1w3;
    const float* b3 = s ? s2b3 : s1b3;
    float* adj = s ? adj2 : adj1;
    uint32_t key_lo = (uint32_t)(s + 1);

    if (t < 32) ((f32x4*)a_l)[t] = ((const f32x4*)(A + i * 128))[t];
    if (t < 32) b2_l[t] = b2[t];
    if (t < 64) w3_l[t] = w3[t];
    if (t < 2)  b3_l[t] = b3[t];
    {   // w2 [128][32] -> bf16 transposed [c][k], swizzled
        int c = t & 31, kq = t >> 5;             // 8 groups x 16 k
        uint32_t* dst = (uint32_t*)w2l;
#pragma unroll
        for (int e = 0; e < 8; ++e) {
            int k = kq * 16 + e * 2;
            uint32_t word = f2bf(w2[k * 32 + c]) | (f2bf(w2[(k + 1) * 32 + c]) << 16);
            int byte = (c * 256 + k * 2) ^ ((c & 7) << 4);
            dst[byte >> 2] = word;
        }
    }
    __syncthreads();                             // a_l ready for z1 build
    // z1 = relu(A[i] + B[j]) -> bf16 LDS, swizzled rows
#pragma unroll
    for (int rep = 0; rep < 4; ++rep) {
        int j = (t >> 2) + rep * 64;
        int kq = t & 3;                          // 32 k each
        const f32x4* bp = (const f32x4*)(B + j * 128 + kq * 32);
        uint32_t words[16];
#pragma unroll
        for (int q = 0; q < 8; ++q) {
            f32x4 bv = bp[q];
            int k = kq * 32 + q * 4;
            float z0 = fmaxf(a_l[k] + bv.x, 0.f);
            float z1v = fmaxf(a_l[k + 1] + bv.y, 0.f);
            float z2v = fmaxf(a_l[k + 2] + bv.z, 0.f);
            float z3v = fmaxf(a_l[k + 3] + bv.w, 0.f);
            words[q * 2]     = f2bf(z0) | (f2bf(z1v) << 16);
            words[q * 2 + 1] = f2bf(z2v) | (f2bf(z3v) << 16);
        }
#pragma unroll
        for (int w4 = 0; w4 < 4; ++w4) {
            int byte = (j * 256 + kq * 64 + w4 * 16) ^ ((j & 7) << 4);
            *(uint4*)(z1z2 + byte) = make_uint4(words[w4 * 4], words[w4 * 4 + 1],
                                                words[w4 * 4 + 2], words[w4 * 4 + 3]);
        }
    }
    __syncthreads();
    // MFMA: z2[256 j][32 c] = z1 @ w2
    int w = t >> 6, l = t & 63;
    bfrag bf[2][4];
#pragma unroll
    for (int ct = 0; ct < 2; ++ct)
#pragma unroll
        for (int ks = 0; ks < 4; ++ks) {
            int col = ct * 16 + (l & 15);
            int k = ks * 32 + (l >> 4) * 8;
            int byte = (col * 256 + k * 2) ^ ((col & 7) << 4);
            bf[ct][ks] = *(bfrag*)(w2l + byte);
        }
    cfrag acc[4][2];
    cfrag zz = {0.f, 0.f, 0.f, 0.f};
#pragma unroll
    for (int rt = 0; rt < 4; ++rt) { acc[rt][0] = zz; acc[rt][1] = zz; }
#pragma unroll
    for (int rt = 0; rt < 4; ++rt) {
        int j = (w * 4 + rt) * 16 + (l & 15);    // A row
#pragma unroll
        for (int ks = 0; ks < 4; ++ks) {
            int byte = (j * 256 + (ks * 32 + (l >> 4) * 8) * 2) ^ ((j & 7) << 4);
            bfrag af = *(bfrag*)(z1z2 + byte);
            acc[rt][0] = __builtin_amdgcn_mfma_f32_16x16x32_bf16(af, bf[0][ks], acc[rt][0], 0, 0, 0);
            acc[rt][1] = __builtin_amdgcn_mfma_f32_16x16x32_bf16(af, bf[1][ks], acc[rt][1], 0, 0, 0);
        }
    }
    __syncthreads();                             // all z1 reads done; reuse as z2
    float* z2 = (float*)z1z2;                    // [256][36] padded
#pragma unroll
    for (int rt = 0; rt < 4; ++rt)
#pragma unroll
        for (int ct = 0; ct < 2; ++ct)
#pragma unroll
            for (int r = 0; r < 4; ++r) {
                int j = (w * 4 + rt) * 16 + (l >> 4) * 4 + r;
                int c = ct * 16 + (l & 15);
                z2[j * 36 + c] = acc[rt][ct][r];
            }
    __syncthreads();
    {   // epilogue: one j per thread
        int j = t;
        float p0 = 0.f, p1 = 0.f;
#pragma unroll
        for (int c = 0; c < 32; ++c) {
            float zv = fmaxf(z2[j * 36 + c] + b2_l[c], 0.f);
            p0 += zv * w3_l[2 * c];
            p1 += zv * w3_l[2 * c + 1];
        }
        float l0 = p0 + b3_l[0], l1 = p1 + b3_l[1];
        uint32_t flat = (uint32_t)(i * 256 + j) * 2u;
        float g0 = jax_gumbel(key_lo, flat);
        float g1 = jax_gumbel(key_lo, flat + 1u);
        adj[i * 256 + j] = (l1 + g1 > l0 + g0) ? 1.0f : 0.0f;
    }
}

// ---------------- GAT attention coefficients ----------------
__global__ void k_attc(const float* __restrict__ H, const float* __restrict__ ai,
                       const float* __restrict__ aj, float* __restrict__ ci,
                       float* __restrict__ cj, int heads, int F) {
    int n = blockIdx.x, lane = threadIdx.x;
    for (int h = 0; h < heads; ++h) {
        float pi = 0.f, pj = 0.f;
        for (int f = lane; f < F; f += 64) {
            float v = H[n * heads * F + h * F + f];
            pi += v * ai[h * F + f];
            pj += v * aj[h * F + f];
        }
        for (int off = 32; off; off >>= 1) {
            pi += __shfl_xor(pi, off);
            pj += __shfl_xor(pj, off);
        }
        if (lane == 0) { ci[n * heads + h] = pi; cj[n * heads + h] = pj; }
    }
}

// ---------------- GAT1: grid (128, 2) — 2 rows, 256-col slice ----------------
__global__ __launch_bounds__(256) void k_gat1(const float* __restrict__ H,
        const float* __restrict__ adj, const float* __restrict__ ci,
        const float* __restrict__ cj, const float* __restrict__ bias,
        float* __restrict__ out) {
    __shared__ float att[2][4][256];
    __shared__ float red[4][2][256];
    int i0 = blockIdx.x * 2, cb = blockIdx.y * 256, t = threadIdx.x;
#pragma unroll
    for (int r = 0; r < 2; ++r) {
        int i = i0 + r;
        float adjv = (t == i) ? 1.f : adj[i * 256 + t];
#pragma unroll
        for (int h = 0; h < 4; ++h) {
            float e = ci[i * 4 + h] + cj[t * 4 + h];
            e = e >= 0.f ? e : 0.2f * e;
            att[r][h][t] = adjv > 0.f ? e : -INFINITY;
        }
    }
    __syncthreads();
    {
        int wv = t >> 6, lane = t & 63;
        for (int p = wv; p < 8; p += 4) {
            int r = p >> 2, h = p & 3;
            float* ar = att[r][h];
            float m = -INFINITY;
            for (int j = lane; j < 256; j += 64) m = fmaxf(m, ar[j]);
            for (int off = 32; off; off >>= 1) m = fmaxf(m, __shfl_xor(m, off));
            float vals[4], sm = 0.f;
#pragma unroll
            for (int q = 0; q < 4; ++q) {
                float v = expf(ar[lane + 64 * q] - m);
                vals[q] = v; sm += v;
            }
            for (int off = 32; off; off >>= 1) sm += __shfl_xor(sm, off);
            float inv = 1.f / sm;
#pragma unroll
            for (int q = 0; q < 4; ++q) ar[lane + 64 * q] = vals[q] * inv;
        }
    }
    __syncthreads();
    {
        int q = t & 63, js = t >> 6;
        int c = cb + q * 4;
        int h = c >> 7;
        f32x4 a0 = {0.f, 0.f, 0.f, 0.f}, a1 = a0;
        const float* ar0 = att[0][h];
        const float* ar1 = att[1][h];
#pragma unroll
        for (int j = js * 64; j < js * 64 + 64; ++j) {
            f32x4 hv = *(const f32x4*)(H + j * 512 + c);
            float v0 = ar0[j], v1 = ar1[j];
            a0.x += v0 * hv.x; a0.y += v0 * hv.y; a0.z += v0 * hv.z; a0.w += v0 * hv.w;
            a1.x += v1 * hv.x; a1.y += v1 * hv.y; a1.z += v1 * hv.z; a1.w += v1 * hv.w;
        }
        *(f32x4*)&red[js][0][q * 4] = a0;
        *(f32x4*)&red[js][1][q * 4] = a1;
    }
    __syncthreads();
#pragma unroll
    for (int rep = 0; rep < 2; ++rep) {
        int o = t + rep * 256;
        int r = o >> 8, c = o & 255;
        float s = red[0][r][c] + red[1][r][c] + red[2][r][c] + red[3][r][c] + bias[cb + c];
        out[(i0 + r) * 512 + cb + c] = s > 0.f ? s : expm1f(s);
    }
}

// ---------------- final: GAT2 + message-decode + value/action heads ----------------
__global__ __launch_bounds__(256) void k_final(const float* __restrict__ H,
        const float* __restrict__ adj, const float* __restrict__ ci,
        const float* __restrict__ cj, const float* __restrict__ g2_b,
        const float* __restrict__ w_md, const float* __restrict__ b_md,
        const float* __restrict__ h_new,
        const float* __restrict__ w_v, const float* __restrict__ b_v,
        const float* __restrict__ w_a, const float* __restrict__ b_a,
        float* __restrict__ value, float* __restrict__ action) {
    __shared__ float att[256];
    __shared__ float buf[4][256];
    __shared__ float out2[256];
    __shared__ float comm3[256];
    int i = blockIdx.x, t = threadIdx.x;
    {
        float adjv = (t == i) ? 1.f : adj[i * 256 + t];
        float e = ci[i] + cj[t];
        e = e >= 0.f ? e : 0.2f * e;
        att[t] = adjv > 0.f ? e : -INFINITY;
    }
    __syncthreads();
    {
        int lane = t & 63;
        float m = -INFINITY;
        for (int j = lane; j < 256; j += 64) m = fmaxf(m, att[j]);
        for (int off = 32; off; off >>= 1) m = fmaxf(m, __shfl_xor(m, off));
        float sm = 0.f;
        for (int j = lane; j < 256; j += 64) sm += expf(att[j] - m);
        for (int off = 32; off; off >>= 1) sm += __shfl_xor(sm, off);
        float inv = 1.f / sm;
        float myval = expf(att[t] - m) * inv;
        __syncthreads();
        att[t] = myval;
    }
    __syncthreads();
    {   // aggregate: out2 = att @ H (+ g2_b)
        int q = t & 63, js = t >> 6;
        f32x4 acc = {0.f, 0.f, 0.f, 0.f};
#pragma unroll
        for (int j = js * 64; j < js * 64 + 64; ++j) {
            f32x4 hv = *(const f32x4*)(H + j * 256 + q * 4);
            float av = att[j];
            acc.x += av * hv.x; acc.y += av * hv.y; acc.z += av * hv.z; acc.w += av * hv.w;
        }
        *(f32x4*)&buf[js][q * 4] = acc;
    }
    __syncthreads();
    out2[t] = buf[0][t] + buf[1][t] + buf[2][t] + buf[3][t] + g2_b[t];
    __syncthreads();
    {   // comm3 = out2 @ w_md + b_md
        int q = t & 63, ks = t >> 6;
        f32x4 acc = {0.f, 0.f, 0.f, 0.f};
#pragma unroll
        for (int k = ks * 64; k < ks * 64 + 64; ++k) {
            f32x4 wv = *(const f32x4*)(w_md + k * 256 + q * 4);
            float xv = out2[k];
            acc.x += xv * wv.x; acc.y += xv * wv.y; acc.z += xv * wv.z; acc.w += xv * wv.w;
        }
        *(f32x4*)&buf[ks][q * 4] = acc;
    }
    __syncthreads();
    comm3[t] = buf[0][t] + buf[1][t] + buf[2][t] + buf[3][t] + b_md[t];
    __syncthreads();
    if (t < 64) {
        int lane = t;
        float p = 0.f;
        for (int k = lane; k < 256; k += 64)
            p += h_new[i * 256 + k] * w_v[k] + comm3[k] * w_v[256 + k];
        for (int off = 32; off; off >>= 1) p += __shfl_xor(p, off);
        if (lane == 0) value[i] = p + b_v[0];

        int o = lane & 15, ks = lane >> 4;
        float acc = 0.f;
        if (o < 10) {
            for (int k = ks * 128; k < ks * 128 + 128; ++k) {
                float x = (k < 256) ? h_new[i * 256 + k] : comm3[k - 256];
                acc += x * w_a[k * 10 + o];
            }
        }
        acc += __shfl_xor(acc, 16);
        acc += __shfl_xor(acc, 32);
        float logit = (o < 10) ? acc + b_a[o] : -INFINITY;
        float m = logit;
        for (int off = 8; off; off >>= 1) m = fmaxf(m, __shfl_xor(m, off));
        float ex = (o < 10) ? expf(logit - m) : 0.f;
        float sm = ex;
        for (int off = 8; off; off >>= 1) sm += __shfl_xor(sm, off);
        if (ks == 0 && o < 10) action[i * 10 + o] = logit - m - logf(sm);
    }
}

extern "C" void kernel_launch(void* const* d_in, const int* in_sizes, int n_in,
                              void* d_out, int out_size, void* d_ws, size_t ws_size,
                              hipStream_t stream) {
    const float* obs   = (const float*)d_in[0];
    const float* hs    = (const float*)d_in[1];
    const float* cs    = (const float*)d_in[2];
    const float* w_obs = (const float*)d_in[3];
    const float* b_obs = (const float*)d_in[4];
    const float* w_ih  = (const float*)d_in[5];
    const float* b_ih  = (const float*)d_in[6];
    const float* w_hh  = (const float*)d_in[7];
    const float* b_hh  = (const float*)d_in[8];
    const float* w_me  = (const float*)d_in[9];
    const float* b_me  = (const float*)d_in[10];
    const float* w_md  = (const float*)d_in[11];
    const float* b_md  = (const float*)d_in[12];
    const float* s1_w1 = (const float*)d_in[13];
    const float* s1_b1 = (const float*)d_in[14];
    const float* s1_w2 = (const float*)d_in[15];
    const float* s1_b2 = (const float*)d_in[16];
    const float* s1_w3 = (const float*)d_in[17];
    const float* s1_b3 = (const float*)d_in[18];
    const float* s2_w1 = (const float*)d_in[19];
    const float* s2_b1 = (const float*)d_in[20];
    const float* s2_w2 = (const float*)d_in[21];
    const float* s2_b2 = (const float*)d_in[22];
    const float* s2_w3 = (const float*)d_in[23];
    const float* s2_b3 = (const float*)d_in[24];
    const float* g1_w  = (const float*)d_in[25];
    const float* g1_ai = (const float*)d_in[26];
    const float* g1_aj = (const float*)d_in[27];
    const float* g1_b  = (const float*)d_in[28];
    const float* g2_w  = (const float*)d_in[29];
    const float* g2_ai = (const float*)d_in[30];
    const float* g2_aj = (const float*)d_in[31];
    const float* g2_b  = (const float*)d_in[32];
    const float* w_v   = (const float*)d_in[33];
    const float* b_v   = (const float*)d_in[34];
    const float* w_a   = (const float*)d_in[35];
    const float* b_a   = (const float*)d_in[36];

    float* out = (float*)d_out;
    float* action = out;               // [1,256,10] = 2560
    float* value  = out + 2560;        // [256,1]
    float* h_new  = out + 2816;        // [256,256]
    float* c_new  = out + 68352;       // [256,256]

    float* ws = (float*)d_ws;
    float* comm  = ws;                 // 65536
    float* A1    = ws + 65536;         // 32768
    float* B1    = ws + 98304;         // 32768
    float* A2    = ws + 131072;        // 32768
    float* B2    = ws + 163840;        // 32768
    float* adj1  = ws + 196608;        // 65536
    float* adj2  = ws + 262144;        // 65536
    float* h1    = ws + 327680;        // 131072
    float* ci1   = ws + 458752;        // 1024
    float* cj1   = ws + 459776;        // 1024
    float* comm2 = ws + 460800;        // 131072
    float* h2    = ws + 591872;        // 65536
    float* ci2   = ws + 657408;        // 256
    float* cj2   = ws + 657664;        // 256

    k_lstm<<<dim3(32, 8), 256, 0, stream>>>(obs, hs, cs, w_obs, b_obs,
                                            w_ih, b_ih, w_hh, b_hh, h_new, c_new);
    k_gemm<256><<<dim3(32, 4), 256, 0, stream>>>(h_new, 256, w_me, 256, b_me, comm, 256);
    k_mgemm<<<dim3(32, 16), 256, 0, stream>>>(comm, g1_w, s1_w1, s1_b1, s2_w1, s2_b1,
                                              h1, A1, B1, A2, B2);
    k_sched<<<dim3(256, 2), 256, 0, stream>>>(A1, B1, s1_w2, s1_b2, s1_w3, s1_b3,
                                              A2, B2, s2_w2, s2_b2, s2_w3, s2_b3,
                                              adj1, adj2);
    k_attc<<<NA, 64, 0, stream>>>(h1, g1_ai, g1_aj, ci1, cj1, 4, 128);
    k_gat1<<<dim3(128, 2), 256, 0, stream>>>(h1, adj1, ci1, cj1, g1_b, comm2);
    k_gemm<512><<<dim3(32, 4), 256, 0, stream>>>(comm2, 512, g2_w, 256, nullptr, h2, 256);
    k_attc<<<NA, 64, 0, stream>>>(h2, g2_ai, g2_aj, ci2, cj2, 1, 256);
    k_final<<<NA, 256, 0, stream>>>(h2, adj2, ci2, cj2, g2_b, w_md, b_md, h_new,
                                    w_v, b_v, w_a, b_a, value, action);
}

// Round 6
// 73.708 us; speedup vs baseline: 5.8543x; 1.3020x over previous
//
#include <hip/hip_runtime.h>
#include <stdint.h>
#include <math.h>

#define NA 256

typedef __attribute__((ext_vector_type(4))) float f32x4;
typedef __attribute__((ext_vector_type(8))) short bfrag;   // 8 bf16 (4 VGPRs)
typedef __attribute__((ext_vector_type(4))) float cfrag;   // MFMA accum

// ---------------- threefry2x32 (JAX-exact) ----------------
__device__ __forceinline__ uint32_t rotl32_(uint32_t v, int d) {
    return (v << d) | (v >> (32 - d));
}

__device__ uint32_t jax_random_bits(uint32_t key_lo, uint32_t flat) {
    uint32_t a, b;
    bool first;
    if (flat < 65536u) { a = flat; b = flat + 65536u; first = true; }
    else               { a = flat - 65536u; b = flat; first = false; }
    uint32_t ks0 = 0u, ks1 = key_lo, ks2 = 0u ^ key_lo ^ 0x1BD11BDAu;
    uint32_t x0 = a + ks0, x1 = b + ks1;
    const int r0[4] = {13, 15, 26, 6};
    const int r1[4] = {17, 29, 16, 24};
#define TF_R4(RS) { for (int rr = 0; rr < 4; ++rr) { x0 += x1; x1 = rotl32_(x1, RS[rr]); x1 ^= x0; } }
    TF_R4(r0); x0 += ks1; x1 += ks2 + 1u;
    TF_R4(r1); x0 += ks2; x1 += ks0 + 2u;
    TF_R4(r0); x0 += ks0; x1 += ks1 + 3u;
    TF_R4(r1); x0 += ks1; x1 += ks2 + 4u;
    TF_R4(r0); x0 += ks2; x1 += ks0 + 5u;
#undef TF_R4
    return first ? x0 : x1;
}

__device__ float jax_gumbel(uint32_t key_lo, uint32_t flat) {
    uint32_t bits = jax_random_bits(key_lo, flat);
    uint32_t v = (bits >> 9) | 0x3F800000u;
    float u = __uint_as_float(v) - 1.0f;
    u = u + 1e-10f;
    u = fmaxf(1e-10f, u);
    return -logf(-logf(u));
}

__device__ __forceinline__ uint32_t f2bf(float f) {   // RNE f32->bf16 bits
    uint32_t u = __float_as_uint(f);
    return (u + 0x7FFFu + ((u >> 16) & 1u)) >> 16;
}

// ---------------- fused obs-proj + LSTM cell ----------------
// grid (32, 8): 8 rows, 32 hid-cols (=128 gate-cols) per block
__global__ __launch_bounds__(256) void k_lstm(
        const float* __restrict__ obs, const float* __restrict__ hs,
        const float* __restrict__ cs,
        const float* __restrict__ w_obs, const float* __restrict__ b_obs,
        const float* __restrict__ w_ih, const float* __restrict__ b_ih,
        const float* __restrict__ w_hh, const float* __restrict__ b_hh,
        float* __restrict__ h_out, float* __restrict__ c_out) {
    __shared__ float o_l[8][128];
    __shared__ float h_l[8][256];
    __shared__ float x_l[8][256];
    __shared__ float red[8192];            // 32KB, reused by both phases
    int r0 = blockIdx.x * 8, c0 = blockIdx.y * 32, t = threadIdx.x;
    ((f32x4*)o_l)[t] = ((const f32x4*)(obs + r0 * 128))[t];
    ((f32x4*)h_l)[t] = ((const f32x4*)(hs + r0 * 256))[t];
    ((f32x4*)h_l)[t + 256] = ((const f32x4*)(hs + r0 * 256))[t + 256];
    __syncthreads();
    // obs proj: x = obs @ w_obs + b_obs  (8 rows x 256 cols)
    {
        int ks = t >> 6, q = t & 63;       // 4 k-splits x 64 col-quads
        f32x4 acc[8];
#pragma unroll
        for (int r = 0; r < 8; ++r) acc[r] = (f32x4){0.f, 0.f, 0.f, 0.f};
#pragma unroll
        for (int k = ks * 32; k < ks * 32 + 32; ++k) {
            f32x4 w = *(const f32x4*)(w_obs + k * 256 + q * 4);
#pragma unroll
            for (int r = 0; r < 8; ++r) {
                float xv = o_l[r][k];
                acc[r].x += xv * w.x; acc[r].y += xv * w.y;
                acc[r].z += xv * w.z; acc[r].w += xv * w.w;
            }
        }
#pragma unroll
        for (int r = 0; r < 8; ++r)
            *(f32x4*)&red[(ks * 8 + r) * 256 + q * 4] = acc[r];
    }
    __syncthreads();
    {
#pragma unroll
        for (int rep = 0; rep < 8; ++rep) {
            int o = t + rep * 256;
            int r = o >> 8, c = o & 255;
            float s = b_obs[c];
#pragma unroll
            for (int k2 = 0; k2 < 4; ++k2) s += red[(k2 * 8 + r) * 256 + c];
            x_l[r][c] = s;
        }
    }
    __syncthreads();
    // gates: [8 rows] x [4 gates x 32 hid-cols], K = 512 (x:256, h:256)
    {
        int ks = t >> 5, cg = t & 31;      // 8 k-splits x (4 gates x 8 quads)
        int g = cg >> 3, qd = cg & 7;
        int col = g * 256 + c0 + qd * 4;
        const float* W = (ks < 4) ? w_ih : w_hh;
        const float* xl = (ks < 4) ? &x_l[0][0] : &h_l[0][0];
        int kb = (ks & 3) * 64;
        f32x4 acc[8];
#pragma unroll
        for (int r = 0; r < 8; ++r) acc[r] = (f32x4){0.f, 0.f, 0.f, 0.f};
#pragma unroll
        for (int kk = 0; kk < 64; ++kk) {
            int k = kb + kk;
            f32x4 w = *(const f32x4*)(W + k * 1024 + col);
#pragma unroll
            for (int r = 0; r < 8; ++r) {
                float xv = xl[r * 256 + k];
                acc[r].x += xv * w.x; acc[r].y += xv * w.y;
                acc[r].z += xv * w.z; acc[r].w += xv * w.w;
            }
        }
        __syncthreads();                   // red reuse safe
#pragma unroll
        for (int r = 0; r < 8; ++r)
            *(f32x4*)&red[(ks * 8 + r) * 128 + cg * 4] = acc[r];
    }
    __syncthreads();
    {
        int r = t >> 5, hc = t & 31;
        int gc = c0 + hc;
        float gate[4];
#pragma unroll
        for (int g = 0; g < 4; ++g) {
            float s = b_ih[g * 256 + gc] + b_hh[g * 256 + gc];
#pragma unroll
            for (int ks = 0; ks < 8; ++ks) s += red[(ks * 8 + r) * 128 + g * 32 + hc];
            gate[g] = s;
        }
        float ig = 1.f / (1.f + expf(-gate[0]));
        float fg = 1.f / (1.f + expf(-gate[1]));
        float gg = tanhf(gate[2]);
        float og = 1.f / (1.f + expf(-gate[3]));
        float cn = fg * cs[(r0 + r) * 256 + gc] + ig * gg;
        float hn = og * tanhf(cn);
        h_out[(r0 + r) * 256 + gc] = hn;
        c_out[(r0 + r) * 256 + gc] = cn;
    }
}

// ---------------- generic 8-row x 64-col GEMM tile ----------------
template<int K>
__device__ __forceinline__ void gemm_core(const float* __restrict__ X, int xs, int r0,
                                          const float* __restrict__ W, int ws,
                                          const float* __restrict__ bias,
                                          float* __restrict__ Y, int ys, int t,
                                          float* xr, float* red) {
    constexpr int KQ = K / 4;
#pragma unroll
    for (int q = t; q < 2 * K; q += 256) {
        int r = q / KQ, c = q % KQ;
        ((f32x4*)xr)[r * KQ + c] = ((const f32x4*)(X + (r0 + r) * xs))[c];
    }
    __syncthreads();
    constexpr int KP = K / 16;
    int qd = t & 15, ks = t >> 4;
    f32x4 acc[8];
#pragma unroll
    for (int r = 0; r < 8; ++r) acc[r] = (f32x4){0.f, 0.f, 0.f, 0.f};
#pragma unroll
    for (int k = ks * KP; k < ks * KP + KP; ++k) {
        f32x4 w = *(const f32x4*)(W + k * ws + qd * 4);
#pragma unroll
        for (int r = 0; r < 8; ++r) {
            float xv = xr[r * K + k];
            acc[r].x += xv * w.x; acc[r].y += xv * w.y;
            acc[r].z += xv * w.z; acc[r].w += xv * w.w;
        }
    }
#pragma unroll
    for (int r = 0; r < 8; ++r)
        *(f32x4*)&red[(ks * 8 + r) * 64 + qd * 4] = acc[r];
    __syncthreads();
#pragma unroll
    for (int rep = 0; rep < 2; ++rep) {
        int o = t + rep * 256;
        int r = o >> 6, c = o & 63;
        float s = bias ? bias[c] : 0.f;
#pragma unroll
        for (int ks2 = 0; ks2 < 16; ++ks2) s += red[(ks2 * 8 + r) * 64 + c];
        Y[(r0 + r) * ys + c] = s;
    }
}

template<int K>
__global__ __launch_bounds__(256) void k_gemm(const float* __restrict__ X, int xs,
                                              const float* __restrict__ W, int ws,
                                              const float* __restrict__ bias,
                                              float* __restrict__ Y, int ys) {
    __shared__ float xr[8 * K];
    __shared__ float red[16 * 8 * 64];
    int cb = blockIdx.y * 64;
    gemm_core<K>(X, xs, blockIdx.x * 8, W + cb, ws, bias ? bias + cb : nullptr,
                 Y + cb, ys, threadIdx.x, xr, red);
}

// multi-target GEMM from comm: y<8 -> h1 slices; y>=8 -> A1,B1,A2,B2 halves
__global__ __launch_bounds__(256) void k_mgemm(const float* __restrict__ comm,
        const float* __restrict__ g1_w,
        const float* __restrict__ s1w1, const float* __restrict__ s1b1,
        const float* __restrict__ s2w1, const float* __restrict__ s2b1,
        float* __restrict__ h1, float* __restrict__ A1, float* __restrict__ B1,
        float* __restrict__ A2, float* __restrict__ B2) {
    __shared__ float xr[8 * 256];
    __shared__ float red[16 * 8 * 64];
    int y = blockIdx.y;
    const float* W; int ws; const float* bias; float* Y; int ys;
    if (y < 8) {
        W = g1_w + y * 64; ws = 512; bias = nullptr; Y = h1 + y * 64; ys = 512;
    } else {
        int idx = y - 8;
        int sel = idx >> 2, part = (idx >> 1) & 1, half = idx & 1;
        W = (sel ? s2w1 : s1w1) + part * (256 * 128) + half * 64; ws = 128;
        bias = part ? nullptr : ((sel ? s2b1 : s1b1) + half * 64);
        float* tgt = sel ? (part ? B2 : A2) : (part ? B1 : A1);
        Y = tgt + half * 64; ys = 128;
    }
    gemm_core<256>(comm, 256, blockIdx.x * 8, W, ws, bias, Y, ys, threadIdx.x, xr, red);
}

// ---------------- scheduler: z1(bf16,LDS) -> MFMA z2 -> logits -> gumbel argmax ----------------
// grid (256, 2): block = (agent i, scheduler s)
__global__ __launch_bounds__(256) void k_sched(
        const float* __restrict__ A1, const float* __restrict__ B1,
        const float* __restrict__ s1w2, const float* __restrict__ s1b2,
        const float* __restrict__ s1w3, const float* __restrict__ s1b3,
        const float* __restrict__ A2, const float* __restrict__ B2,
        const float* __restrict__ s2w2, const float* __restrict__ s2b2,
        const float* __restrict__ s2w3, const float* __restrict__ s2b3,
        float* __restrict__ adj1, float* __restrict__ adj2) {
    __shared__ __align__(16) char z1z2[65536];   // z1 bf16 [256][128] swz | z2 f32 [256][36]
    __shared__ __align__(16) char w2l[8192];     // w2^T bf16 [32][128] swz
    __shared__ float a_l[128];
    __shared__ float b2_l[32], w3_l[64], b3_l[2];
    int i = blockIdx.x, t = threadIdx.x, s = blockIdx.y;
    const float* A  = s ? A2 : A1;
    const float* B  = s ? B2 : B1;
    const float* w2 = s ? s2w2 : s1w2;
    const float* b2 = s ? s2b2 : s1b2;
    const float* w3 = s ? s2w3 : s1w3;
    const float* b3 = s ? s2b3 : s1b3;
    float* adj = s ? adj2 : adj1;
    uint32_t key_lo = (uint32_t)(s + 1);

    if (t < 32) ((f32x4*)a_l)[t] = ((const f32x4*)(A + i * 128))[t];
    if (t < 32) b2_l[t] = b2[t];
    if (t < 64) w3_l[t] = w3[t];
    if (t < 2)  b3_l[t] = b3[t];
    {   // w2 [128][32] -> bf16 transposed [c][k], swizzled
        int c = t & 31, kq = t >> 5;             // 8 groups x 16 k
        uint32_t* dst = (uint32_t*)w2l;
#pragma unroll
        for (int e = 0; e < 8; ++e) {
            int k = kq * 16 + e * 2;
            uint32_t word = f2bf(w2[k * 32 + c]) | (f2bf(w2[(k + 1) * 32 + c]) << 16);
            int byte = (c * 256 + k * 2) ^ ((c & 7) << 4);
            dst[byte >> 2] = word;
        }
    }
    __syncthreads();                             // a_l ready for z1 build
    // z1 = relu(A[i] + B[j]) -> bf16 LDS, swizzled rows
#pragma unroll
    for (int rep = 0; rep < 4; ++rep) {
        int j = (t >> 2) + rep * 64;
        int kq = t & 3;                          // 32 k each
        const f32x4* bp = (const f32x4*)(B + j * 128 + kq * 32);
        uint32_t words[16];
#pragma unroll
        for (int q = 0; q < 8; ++q) {
            f32x4 bv = bp[q];
            int k = kq * 32 + q * 4;
            float z0 = fmaxf(a_l[k] + bv.x, 0.f);
            float z1v = fmaxf(a_l[k + 1] + bv.y, 0.f);
            float z2v = fmaxf(a_l[k + 2] + bv.z, 0.f);
            float z3v = fmaxf(a_l[k + 3] + bv.w, 0.f);
            words[q * 2]     = f2bf(z0) | (f2bf(z1v) << 16);
            words[q * 2 + 1] = f2bf(z2v) | (f2bf(z3v) << 16);
        }
#pragma unroll
        for (int w4 = 0; w4 < 4; ++w4) {
            int byte = (j * 256 + kq * 64 + w4 * 16) ^ ((j & 7) << 4);
            *(uint4*)(z1z2 + byte) = make_uint4(words[w4 * 4], words[w4 * 4 + 1],
                                                words[w4 * 4 + 2], words[w4 * 4 + 3]);
        }
    }
    __syncthreads();
    // MFMA: z2[256 j][32 c] = z1 @ w2
    int w = t >> 6, l = t & 63;
    bfrag bf[2][4];
#pragma unroll
    for (int ct = 0; ct < 2; ++ct)
#pragma unroll
        for (int ks = 0; ks < 4; ++ks) {
            int col = ct * 16 + (l & 15);
            int k = ks * 32 + (l >> 4) * 8;
            int byte = (col * 256 + k * 2) ^ ((col & 7) << 4);
            bf[ct][ks] = *(bfrag*)(w2l + byte);
        }
    cfrag acc[4][2];
    cfrag zz = {0.f, 0.f, 0.f, 0.f};
#pragma unroll
    for (int rt = 0; rt < 4; ++rt) { acc[rt][0] = zz; acc[rt][1] = zz; }
#pragma unroll
    for (int rt = 0; rt < 4; ++rt) {
        int j = (w * 4 + rt) * 16 + (l & 15);    // A row
#pragma unroll
        for (int ks = 0; ks < 4; ++ks) {
            int byte = (j * 256 + (ks * 32 + (l >> 4) * 8) * 2) ^ ((j & 7) << 4);
            bfrag af = *(bfrag*)(z1z2 + byte);
            acc[rt][0] = __builtin_amdgcn_mfma_f32_16x16x32_bf16(af, bf[0][ks], acc[rt][0], 0, 0, 0);
            acc[rt][1] = __builtin_amdgcn_mfma_f32_16x16x32_bf16(af, bf[1][ks], acc[rt][1], 0, 0, 0);
        }
    }
    __syncthreads();                             // all z1 reads done; reuse as z2
    float* z2 = (float*)z1z2;                    // [256][36] padded
#pragma unroll
    for (int rt = 0; rt < 4; ++rt)
#pragma unroll
        for (int ct = 0; ct < 2; ++ct)
#pragma unroll
            for (int r = 0; r < 4; ++r) {
                int j = (w * 4 + rt) * 16 + (l >> 4) * 4 + r;
                int c = ct * 16 + (l & 15);
                z2[j * 36 + c] = acc[rt][ct][r];
            }
    __syncthreads();
    {   // epilogue: one j per thread
        int j = t;
        float p0 = 0.f, p1 = 0.f;
#pragma unroll
        for (int c = 0; c < 32; ++c) {
            float zv = fmaxf(z2[j * 36 + c] + b2_l[c], 0.f);
            p0 += zv * w3_l[2 * c];
            p1 += zv * w3_l[2 * c + 1];
        }
        float l0 = p0 + b3_l[0], l1 = p1 + b3_l[1];
        uint32_t flat = (uint32_t)(i * 256 + j) * 2u;
        float g0 = jax_gumbel(key_lo, flat);
        float g1 = jax_gumbel(key_lo, flat + 1u);
        adj[i * 256 + j] = (l1 + g1 > l0 + g0) ? 1.0f : 0.0f;
    }
}

// ---------------- GAT attention coefficients ----------------
__global__ void k_attc(const float* __restrict__ H, const float* __restrict__ ai,
                       const float* __restrict__ aj, float* __restrict__ ci,
                       float* __restrict__ cj, int heads, int F) {
    int n = blockIdx.x, lane = threadIdx.x;
    for (int h = 0; h < heads; ++h) {
        float pi = 0.f, pj = 0.f;
        for (int f = lane; f < F; f += 64) {
            float v = H[n * heads * F + h * F + f];
            pi += v * ai[h * F + f];
            pj += v * aj[h * F + f];
        }
        for (int off = 32; off; off >>= 1) {
            pi += __shfl_xor(pi, off);
            pj += __shfl_xor(pj, off);
        }
        if (lane == 0) { ci[n * heads + h] = pi; cj[n * heads + h] = pj; }
    }
}

// ---------------- GAT1: grid (128, 2) — 2 rows, 256-col slice ----------------
__global__ __launch_bounds__(256) void k_gat1(const float* __restrict__ H,
        const float* __restrict__ adj, const float* __restrict__ ci,
        const float* __restrict__ cj, const float* __restrict__ bias,
        float* __restrict__ out) {
    __shared__ float att[2][4][256];
    __shared__ float red[4][2][256];
    int i0 = blockIdx.x * 2, cb = blockIdx.y * 256, t = threadIdx.x;
#pragma unroll
    for (int r = 0; r < 2; ++r) {
        int i = i0 + r;
        float adjv = (t == i) ? 1.f : adj[i * 256 + t];
#pragma unroll
        for (int h = 0; h < 4; ++h) {
            float e = ci[i * 4 + h] + cj[t * 4 + h];
            e = e >= 0.f ? e : 0.2f * e;
            att[r][h][t] = adjv > 0.f ? e : -INFINITY;
        }
    }
    __syncthreads();
    {
        int wv = t >> 6, lane = t & 63;
        for (int p = wv; p < 8; p += 4) {
            int r = p >> 2, h = p & 3;
            float* ar = att[r][h];
            float m = -INFINITY;
            for (int j = lane; j < 256; j += 64) m = fmaxf(m, ar[j]);
            for (int off = 32; off; off >>= 1) m = fmaxf(m, __shfl_xor(m, off));
            float vals[4], sm = 0.f;
#pragma unroll
            for (int q = 0; q < 4; ++q) {
                float v = expf(ar[lane + 64 * q] - m);
                vals[q] = v; sm += v;
            }
            for (int off = 32; off; off >>= 1) sm += __shfl_xor(sm, off);
            float inv = 1.f / sm;
#pragma unroll
            for (int q = 0; q < 4; ++q) ar[lane + 64 * q] = vals[q] * inv;
        }
    }
    __syncthreads();
    {
        int q = t & 63, js = t >> 6;
        int c = cb + q * 4;
        int h = c >> 7;
        f32x4 a0 = {0.f, 0.f, 0.f, 0.f}, a1 = a0;
        const float* ar0 = att[0][h];
        const float* ar1 = att[1][h];
#pragma unroll
        for (int j = js * 64; j < js * 64 + 64; ++j) {
            f32x4 hv = *(const f32x4*)(H + j * 512 + c);
            float v0 = ar0[j], v1 = ar1[j];
            a0.x += v0 * hv.x; a0.y += v0 * hv.y; a0.z += v0 * hv.z; a0.w += v0 * hv.w;
            a1.x += v1 * hv.x; a1.y += v1 * hv.y; a1.z += v1 * hv.z; a1.w += v1 * hv.w;
        }
        *(f32x4*)&red[js][0][q * 4] = a0;
        *(f32x4*)&red[js][1][q * 4] = a1;
    }
    __syncthreads();
#pragma unroll
    for (int rep = 0; rep < 2; ++rep) {
        int o = t + rep * 256;
        int r = o >> 8, c = o & 255;
        float s = red[0][r][c] + red[1][r][c] + red[2][r][c] + red[3][r][c] + bias[cb + c];
        out[(i0 + r) * 512 + cb + c] = s > 0.f ? s : expm1f(s);
    }
}

// ---------------- final: GAT2 + message-decode + value/action heads ----------------
__global__ __launch_bounds__(256) void k_final(const float* __restrict__ H,
        const float* __restrict__ adj, const float* __restrict__ ci,
        const float* __restrict__ cj, const float* __restrict__ g2_b,
        const float* __restrict__ w_md, const float* __restrict__ b_md,
        const float* __restrict__ h_new,
        const float* __restrict__ w_v, const float* __restrict__ b_v,
        const float* __restrict__ w_a, const float* __restrict__ b_a,
        float* __restrict__ value, float* __restrict__ action) {
    __shared__ float att[256];
    __shared__ float buf[4][256];
    __shared__ float out2[256];
    __shared__ float comm3[256];
    __shared__ float hrow[256];
    __shared__ float hred[4][16];
    __shared__ float vred[4];
    int i = blockIdx.x, t = threadIdx.x;
    hrow[t] = h_new[i * 256 + t];
    {
        float adjv = (t == i) ? 1.f : adj[i * 256 + t];
        float e = ci[i] + cj[t];
        e = e >= 0.f ? e : 0.2f * e;
        att[t] = adjv > 0.f ? e : -INFINITY;
    }
    __syncthreads();
    {
        int lane = t & 63;
        float m = -INFINITY;
        for (int j = lane; j < 256; j += 64) m = fmaxf(m, att[j]);
        for (int off = 32; off; off >>= 1) m = fmaxf(m, __shfl_xor(m, off));
        float sm = 0.f;
        for (int j = lane; j < 256; j += 64) sm += expf(att[j] - m);
        for (int off = 32; off; off >>= 1) sm += __shfl_xor(sm, off);
        float inv = 1.f / sm;
        float myval = expf(att[t] - m) * inv;
        __syncthreads();
        att[t] = myval;
    }
    __syncthreads();
    {   // aggregate: out2 = att @ H (+ g2_b)
        int q = t & 63, js = t >> 6;
        f32x4 acc = {0.f, 0.f, 0.f, 0.f};
#pragma unroll
        for (int j = js * 64; j < js * 64 + 64; ++j) {
            f32x4 hv = *(const f32x4*)(H + j * 256 + q * 4);
            float av = att[j];
            acc.x += av * hv.x; acc.y += av * hv.y; acc.z += av * hv.z; acc.w += av * hv.w;
        }
        *(f32x4*)&buf[js][q * 4] = acc;
    }
    __syncthreads();
    out2[t] = buf[0][t] + buf[1][t] + buf[2][t] + buf[3][t] + g2_b[t];
    __syncthreads();
    {   // comm3 = out2 @ w_md + b_md
        int q = t & 63, ks = t >> 6;
        f32x4 acc = {0.f, 0.f, 0.f, 0.f};
#pragma unroll
        for (int k = ks * 64; k < ks * 64 + 64; ++k) {
            f32x4 wv = *(const f32x4*)(w_md + k * 256 + q * 4);
            float xv = out2[k];
            acc.x += xv * wv.x; acc.y += xv * wv.y; acc.z += xv * wv.z; acc.w += xv * wv.w;
        }
        *(f32x4*)&buf[ks][q * 4] = acc;
    }
    __syncthreads();
    comm3[t] = buf[0][t] + buf[1][t] + buf[2][t] + buf[3][t] + b_md[t];
    __syncthreads();
    // ---- heads: all 256 threads ----
    int w = t >> 6, l = t & 63;
    {   // value: k = t (h part) and t+256 (comm part)
        float p = hrow[t] * w_v[t] + comm3[t] * w_v[256 + t];
        for (int off = 32; off; off >>= 1) p += __shfl_xor(p, off);
        if (l == 0) vred[w] = p;
    }
    {   // action: o = l&15 (10 used), kseg = w*4 + (l>>4): 16 segs x 32 k
        int o = l & 15;
        int kseg = w * 4 + (l >> 4);
        float acc = 0.f;
        if (o < 10) {
#pragma unroll
            for (int kk = 0; kk < 32; ++kk) {
                int k = kseg * 32 + kk;
                float x = (kseg < 8) ? hrow[k] : comm3[k - 256];
                acc += x * w_a[k * 10 + o];
            }
        }
        acc += __shfl_xor(acc, 16);
        acc += __shfl_xor(acc, 32);
        if (l < 16) hred[w][l] = acc;        // per-wave partial for output o=l
    }
    __syncthreads();
    if (t < 16) {
        int o = t;
        float logit = (o < 10)
            ? hred[0][o] + hred[1][o] + hred[2][o] + hred[3][o] + b_a[o]
            : -INFINITY;
        float m = logit;
        for (int off = 8; off; off >>= 1) m = fmaxf(m, __shfl_xor(m, off));
        float ex = (o < 10) ? expf(logit - m) : 0.f;
        float sm = ex;
        for (int off = 8; off; off >>= 1) sm += __shfl_xor(sm, off);
        if (o < 10) action[i * 10 + o] = logit - m - logf(sm);
        if (o == 0) value[i] = vred[0] + vred[1] + vred[2] + vred[3] + b_v[0];
    }
}

extern "C" void kernel_launch(void* const* d_in, const int* in_sizes, int n_in,
                              void* d_out, int out_size, void* d_ws, size_t ws_size,
                              hipStream_t stream) {
    const float* obs   = (const float*)d_in[0];
    const float* hs    = (const float*)d_in[1];
    const float* cs    = (const float*)d_in[2];
    const float* w_obs = (const float*)d_in[3];
    const float* b_obs = (const float*)d_in[4];
    const float* w_ih  = (const float*)d_in[5];
    const float* b_ih  = (const float*)d_in[6];
    const float* w_hh  = (const float*)d_in[7];
    const float* b_hh  = (const float*)d_in[8];
    const float* w_me  = (const float*)d_in[9];
    const float* b_me  = (const float*)d_in[10];
    const float* w_md  = (const float*)d_in[11];
    const float* b_md  = (const float*)d_in[12];
    const float* s1_w1 = (const float*)d_in[13];
    const float* s1_b1 = (const float*)d_in[14];
    const float* s1_w2 = (const float*)d_in[15];
    const float* s1_b2 = (const float*)d_in[16];
    const float* s1_w3 = (const float*)d_in[17];
    const float* s1_b3 = (const float*)d_in[18];
    const float* s2_w1 = (const float*)d_in[19];
    const float* s2_b1 = (const float*)d_in[20];
    const float* s2_w2 = (const float*)d_in[21];
    const float* s2_b2 = (const float*)d_in[22];
    const float* s2_w3 = (const float*)d_in[23];
    const float* s2_b3 = (const float*)d_in[24];
    const float* g1_w  = (const float*)d_in[25];
    const float* g1_ai = (const float*)d_in[26];
    const float* g1_aj = (const float*)d_in[27];
    const float* g1_b  = (const float*)d_in[28];
    const float* g2_w  = (const float*)d_in[29];
    const float* g2_ai = (const float*)d_in[30];
    const float* g2_aj = (const float*)d_in[31];
    const float* g2_b  = (const float*)d_in[32];
    const float* w_v   = (const float*)d_in[33];
    const float* b_v   = (const float*)d_in[34];
    const float* w_a   = (const float*)d_in[35];
    const float* b_a   = (const float*)d_in[36];

    float* out = (float*)d_out;
    float* action = out;               // [1,256,10] = 2560
    float* value  = out + 2560;        // [256,1]
    float* h_new  = out + 2816;        // [256,256]
    float* c_new  = out + 68352;       // [256,256]

    float* ws = (float*)d_ws;
    float* comm  = ws;                 // 65536
    float* A1    = ws + 65536;         // 32768
    float* B1    = ws + 98304;         // 32768
    float* A2    = ws + 131072;        // 32768
    float* B2    = ws + 163840;        // 32768
    float* adj1  = ws + 196608;        // 65536
    float* adj2  = ws + 262144;        // 65536
    float* h1    = ws + 327680;        // 131072
    float* ci1   = ws + 458752;        // 1024
    float* cj1   = ws + 459776;        // 1024
    float* comm2 = ws + 460800;        // 131072
    float* h2    = ws + 591872;        // 65536
    float* ci2   = ws + 657408;        // 256
    float* cj2   = ws + 657664;        // 256

    k_lstm<<<dim3(32, 8), 256, 0, stream>>>(obs, hs, cs, w_obs, b_obs,
                                            w_ih, b_ih, w_hh, b_hh, h_new, c_new);
    k_gemm<256><<<dim3(32, 4), 256, 0, stream>>>(h_new, 256, w_me, 256, b_me, comm, 256);
    k_mgemm<<<dim3(32, 16), 256, 0, stream>>>(comm, g1_w, s1_w1, s1_b1, s2_w1, s2_b1,
                                              h1, A1, B1, A2, B2);
    k_sched<<<dim3(256, 2), 256, 0, stream>>>(A1, B1, s1_w2, s1_b2, s1_w3, s1_b3,
                                              A2, B2, s2_w2, s2_b2, s2_w3, s2_b3,
                                              adj1, adj2);
    k_attc<<<NA, 64, 0, stream>>>(h1, g1_ai, g1_aj, ci1, cj1, 4, 128);
    k_gat1<<<dim3(128, 2), 256, 0, stream>>>(h1, adj1, ci1, cj1, g1_b, comm2);
    k_gemm<512><<<dim3(32, 4), 256, 0, stream>>>(comm2, 512, g2_w, 256, nullptr, h2, 256);
    k_attc<<<NA, 64, 0, stream>>>(h2, g2_ai, g2_aj, ci2, cj2, 1, 256);
    k_final<<<NA, 256, 0, stream>>>(h2, adj2, ci2, cj2, g2_b, w_md, b_md, h_new,
                                    w_v, b_v, w_a, b_a, value, action);
}